// Round 5
// baseline (280.496 us; speedup 1.0000x reference)
//
#include <hip/hip_runtime.h>
#include <hip/hip_bf16.h>

#define BB 8
#define SS 4096
#define CC 512
#define NTOK (BB*SS)   // 32768
#define QKVS 1664      // q(512) | k(512) | v(512) | qg(128)

typedef __attribute__((ext_vector_type(8))) short bf16x8;
typedef __attribute__((ext_vector_type(4))) float f32x4;
typedef __attribute__((ext_vector_type(4))) short s16x4;

__device__ __forceinline__ float bf2f(short s) {
  return __uint_as_float(((unsigned)(unsigned short)s) << 16);
}
__device__ __forceinline__ short f2bf(float f) {
  __hip_bfloat16 h = __float2bfloat16(f);
  return *reinterpret_cast<short*>(&h);
}

__device__ __forceinline__ f32x4 pv_mfma(s16x4 a, s16x4 b, f32x4 c) {
#if __has_builtin(__builtin_amdgcn_mfma_f32_16x16x16bf16_1k)
  return __builtin_amdgcn_mfma_f32_16x16x16bf16_1k(a, b, c, 0, 0, 0);
#else
  f32x4 d;
  asm volatile("v_mfma_f32_16x16x16_bf16 %0, %1, %2, %3\n\ts_nop 7\n\ts_nop 7"
               : "=v"(d) : "v"(a), "v"(b), "v"(c));
  return d;
#endif
}

// async global -> LDS, 16B per lane; LDS dest is wave-uniform base + lane*16
__device__ __forceinline__ void gload_lds16(const short* g, short* l) {
  __builtin_amdgcn_global_load_lds(
      (const __attribute__((address_space(1))) unsigned int*)g,
      (__attribute__((address_space(3))) unsigned int*)l, 16, 0, 0);
}

// ---------------- prep: transpose+cast weights, bias concat, bqg, zero bias ----------------
__global__ __launch_bounds__(256) void prep_weights(
    const float* __restrict__ Wq, const float* __restrict__ Wk, const float* __restrict__ Wv,
    const float* __restrict__ Wo, const float* __restrict__ Wg,
    const float* __restrict__ bq, const float* __restrict__ bk, const float* __restrict__ bv,
    const float* __restrict__ bg,
    short* __restrict__ WtQKV, short* __restrict__ WtO, short* __restrict__ WtG,
    short* __restrict__ Wqb, float* __restrict__ bqkv, float* __restrict__ zb)
{
  int i = blockIdx.x * 256 + threadIdx.x;
  if (i < 1536 * 512) {                  // WtQKV[n][k] = W*(k, n%512)
    int n = i >> 9, k = i & 511;
    const float* W = (n < 512) ? Wq : (n < 1024) ? Wk : Wv;
    WtQKV[i] = f2bf(W[k * 512 + (n & 511)]);
  }
  if (i < 512 * 512) {                   // WtO[n][k] = Wo[k][n];  Wqb = bf16(Wq) row-major
    int n = i >> 9, k = i & 511;
    WtO[i] = f2bf(Wo[k * 512 + n]);
    Wqb[i] = f2bf(Wq[i]);
  }
  if (i < 128 * 512) {                   // WtG[n][k] = Wg[k][n]
    int n = i >> 9, k = i & 511;
    WtG[i] = f2bf(Wg[k * 128 + n]);
  }
  if (i < 1536) {
    bqkv[i] = (i < 512) ? bq[i] : (i < 1024) ? bk[i - 512] : bv[i - 1024];
  }
  if (i < 512) zb[i] = 0.f;              // zero bias — FULL 512 cols (fold GEMM N=512)
  if (i < 128) {                         // bqg[n] = bg[n] + sum_c bq[c]*Wg[c][n]
    float s = bg[i];
    for (int c = 0; c < 512; c++) s += bq[c] * Wg[c * 128 + i];
    bqkv[1536 + i] = s;
  }
}

// ---------------- fused: cast x fp32->bf16 + channel pool (avg,max) ----------------
__global__ __launch_bounds__(256) void cast_pool_kernel(const float* __restrict__ x,
                                                        short* __restrict__ xb,
                                                        float* __restrict__ pavg,
                                                        float* __restrict__ pmax)
{
  int tok = blockIdx.x * 4 + (threadIdx.x >> 6);
  int lane = threadIdx.x & 63;
  const float* xr = &x[(size_t)tok * CC];
  float4 a = *(const float4*)&xr[lane * 4];
  float4 b = *(const float4*)&xr[256 + lane * 4];
  s16x4 oa, ob;
  oa[0] = f2bf(a.x); oa[1] = f2bf(a.y); oa[2] = f2bf(a.z); oa[3] = f2bf(a.w);
  ob[0] = f2bf(b.x); ob[1] = f2bf(b.y); ob[2] = f2bf(b.z); ob[3] = f2bf(b.w);
  *(s16x4*)&xb[(size_t)tok * CC + lane * 4] = oa;
  *(s16x4*)&xb[(size_t)tok * CC + 256 + lane * 4] = ob;
  float s = (a.x + a.y) + (a.z + a.w) + (b.x + b.y) + (b.z + b.w);
  float m = fmaxf(fmaxf(fmaxf(a.x, a.y), fmaxf(a.z, a.w)),
                  fmaxf(fmaxf(b.x, b.y), fmaxf(b.z, b.w)));
#pragma unroll
  for (int off = 32; off; off >>= 1) {
    s += __shfl_down(s, off);
    m = fmaxf(m, __shfl_down(m, off));
  }
  if (lane == 0) { pavg[tok] = s * (1.0f / CC); pmax[tok] = m; }
}

// ---------------- bf16 MFMA GEMM, 2-phase double-buffered (T3-minimum) ----------------
// C[M,N] = A[M,K] @ Wt[N,K]^T + bias. tile 128x128, 4 waves (2x2), wave 64x64, BK=32.
// Per phase: STAGE(next tile, other buf) issued BEFORE compute(cur buf); ONE barrier/phase.
template<int OUT_BF16>
__global__ __launch_bounds__(256) void gemm_kernel(
    const short* __restrict__ A, int lda,
    const short* __restrict__ Wt,
    const float* __restrict__ bias,
    void* __restrict__ Cp, int ldc, int K)
{
  __shared__ short As[2][128 * 32];
  __shared__ short Bs[2][128 * 32];
  const int m0 = blockIdx.y * 128;
  const int n0 = blockIdx.x * 128;
  const int t = threadIdx.x;
  const int lane = t & 63, w = t >> 6;
  const int wm = (w >> 1) * 64, wn = (w & 1) * 64;
  const int lr = lane & 15, kb = (lane >> 4) * 8;

  // staging: lane covers row (w*16 + lane/4), elems (lane%4)*8
  const int srow = w * 16 + (lane >> 2);
  const int scol = (lane & 3) * 8;
  const short* Ag0 = A + (size_t)(m0 + srow) * lda + scol;
  const short* Ag1 = Ag0 + (size_t)64 * lda;
  const short* Bg0 = Wt + (size_t)(n0 + srow) * K + scol;
  const short* Bg1 = Bg0 + (size_t)64 * K;
  const int l0 = (w * 16) * 32;          // wave-uniform LDS offsets
  const int l1 = (64 + w * 16) * 32;

  f32x4 acc[4][4];
#pragma unroll
  for (int i = 0; i < 4; i++)
#pragma unroll
    for (int j = 0; j < 4; j++) acc[i][j] = (f32x4){0.f, 0.f, 0.f, 0.f};

#define STAGE(BUF, KOFF)                          \
  do {                                            \
    gload_lds16(Ag0 + (KOFF), &As[BUF][l0]);      \
    gload_lds16(Ag1 + (KOFF), &As[BUF][l1]);      \
    gload_lds16(Bg0 + (KOFF), &Bs[BUF][l0]);      \
    gload_lds16(Bg1 + (KOFF), &Bs[BUF][l1]);      \
  } while (0)

#define COMPUTE(BUF)                                                              \
  do {                                                                            \
    bf16x8 af[4], bfr[4];                                                         \
    _Pragma("unroll")                                                             \
    for (int mt = 0; mt < 4; mt++) af[mt]  = *(bf16x8*)&As[BUF][(wm + mt * 16 + lr) * 32 + kb]; \
    _Pragma("unroll")                                                             \
    for (int nt = 0; nt < 4; nt++) bfr[nt] = *(bf16x8*)&Bs[BUF][(wn + nt * 16 + lr) * 32 + kb]; \
    _Pragma("unroll")                                                             \
    for (int mt = 0; mt < 4; mt++)                                                \
      _Pragma("unroll")                                                           \
      for (int nt = 0; nt < 4; nt++)                                              \
        acc[mt][nt] = __builtin_amdgcn_mfma_f32_16x16x32_bf16(af[mt], bfr[nt], acc[mt][nt], 0, 0, 0); \
  } while (0)

  STAGE(0, 0);
  __syncthreads();                       // drain prologue stage
  for (int k0 = 0; k0 < K; k0 += 64) {
    // phase A: compute buf0 (tile k0), stage buf1 (tile k0+32) underneath
    STAGE(1, k0 + 32);
    COMPUTE(0);
    __syncthreads();
    // phase B: compute buf1, stage buf0 (tile k0+64) underneath
    if (k0 + 64 < K) STAGE(0, k0 + 64);
    COMPUTE(1);
    __syncthreads();
  }
#undef STAGE
#undef COMPUTE

  // epilogue: D mapping col=lane&15, row=(lane>>4)*4+j
  const int cr = (lane >> 4) * 4;
#pragma unroll
  for (int nt = 0; nt < 4; nt++) {
    int col = n0 + wn + nt * 16 + lr;
    float bv = bias[col];
#pragma unroll
    for (int mt = 0; mt < 4; mt++) {
      int row = m0 + wm + mt * 16 + cr;
#pragma unroll
      for (int j = 0; j < 4; j++) {
        float v = acc[mt][nt][j] + bv;
        if (OUT_BF16) ((short*)Cp)[(size_t)(row + j) * ldc + col] = f2bf(v);
        else          ((float*)Cp)[(size_t)(row + j) * ldc + col] = v;
      }
    }
  }
}

// ---------------- windowed attention: MFMA, no LDS ----------------
// Block = 4 waves; 2 windows per block; wave w: window w>>1, col-half w&1.
// Swapped QK^T (A=K, B=Q) -> lane holds S[q=lane&15][key=(lane>>4)*4+jj]; softmax is
// 2x shfl_xor; P lands exactly in the 16x16x16 A-operand layout for PV.
__global__ __launch_bounds__(256) void winattn_kernel(const short* __restrict__ qkvb,
                                                      short* __restrict__ xl)
{
  const int t = threadIdx.x;
  const int lane = t & 63, w = t >> 6;
  const int t0 = (blockIdx.x * 2 + (w >> 1)) * 16;   // window token base
  const int half = w & 1;                            // col half

  const int qrow = lane & 15;
  const int grp8 = (lane >> 4) * 8;
  const int krow = (lane >> 4) * 4;

  const short* kqbase = &qkvb[(size_t)(t0 + qrow) * QKVS];
  f32x4 acc = (f32x4){0.f, 0.f, 0.f, 0.f};
#pragma unroll
  for (int k0 = 0; k0 < 512; k0 += 32) {
    bf16x8 kf = *(const bf16x8*)&kqbase[512 + k0 + grp8];
    bf16x8 qf = *(const bf16x8*)&kqbase[k0 + grp8];
    acc = __builtin_amdgcn_mfma_f32_16x16x32_bf16(kf, qf, acc, 0, 0, 0);
  }

  const float scale = 0.04419417382415922f;  // 1/sqrt(512)
  float s0 = acc[0] * scale, s1 = acc[1] * scale, s2 = acc[2] * scale, s3 = acc[3] * scale;
  float m = fmaxf(fmaxf(s0, s1), fmaxf(s2, s3));
  m = fmaxf(m, __shfl_xor(m, 16));
  m = fmaxf(m, __shfl_xor(m, 32));
  float e0 = __expf(s0 - m), e1 = __expf(s1 - m), e2 = __expf(s2 - m), e3 = __expf(s3 - m);
  float sum = e0 + e1 + e2 + e3;
  sum += __shfl_xor(sum, 16);
  sum += __shfl_xor(sum, 32);
  float inv = 1.0f / sum;
  s16x4 pa;
  pa[0] = f2bf(e0 * inv); pa[1] = f2bf(e1 * inv);
  pa[2] = f2bf(e2 * inv); pa[3] = f2bf(e3 * inv);

  const short* vbase = &qkvb[(size_t)t0 * QKVS + 1024];
  const int colo = lane & 15;
#pragma unroll
  for (int ct = 0; ct < 16; ct++) {
    const int c0 = half * 256 + ct * 16;
    s16x4 bf;
#pragma unroll
    for (int u = 0; u < 4; u++)
      bf[u] = vbase[(size_t)(krow + u) * QKVS + c0 + colo];
    f32x4 d = pv_mfma(pa, bf, (f32x4){0.f, 0.f, 0.f, 0.f});
#pragma unroll
    for (int jj = 0; jj < 4; jj++)
      xl[(size_t)(t0 + krow + jj) * 512 + c0 + colo] = f2bf(d[jj]);
  }
}

// ---------------- kg[b][g][d] = x[b, gidx[g], :] @ Wg + bg  (fp32 exact) ----------------
__global__ __launch_bounds__(256) void kg_kernel(const float* __restrict__ x,
                                                 const float* __restrict__ Wg,
                                                 const float* __restrict__ bg,
                                                 float* __restrict__ kg)
{
  int o = blockIdx.x * 256 + threadIdx.x;   // 4096 outputs
  int d = o & 127, g = (o >> 7) & 3, b = o >> 9;
  const int gidx[4] = {0, 1365, 2730, 4095};
  const float* xr = &x[((size_t)b * SS + gidx[g]) * CC];
  float s = bg[d];
  for (int c = 0; c < CC; c++) s += xr[c] * Wg[c * 128 + d];
  kg[o] = s;
}

// ---------------- kgo[b][g][c] = kg[b][g][:] @ Wgo ----------------
__global__ __launch_bounds__(256) void kgo_kernel(const float* __restrict__ kg,
                                                  const float* __restrict__ Wgo,
                                                  float* __restrict__ kgo)
{
  __shared__ float kr[128];
  int bg_ = blockIdx.x;                 // 0..31
  int t = threadIdx.x;
  if (t < 128) kr[t] = kg[bg_ * 128 + t];
  __syncthreads();
  for (int c = t; c < 512; c += 256) {
    float s = 0.f;
    for (int d = 0; d < 128; d++) s += kr[d] * Wgo[d * 512 + c];
    kgo[bg_ * 512 + c] = s;
  }
}

// ---------------- combine: gattn softmax + conv gate + y = (x+xl+xg)*gate (bf16) ----------------
__global__ __launch_bounds__(256) void combine_kernel(
    const short* __restrict__ xb, const short* __restrict__ qkvb,
    const float* __restrict__ kg, const float* __restrict__ kgo,
    const float* __restrict__ bgo, const float* __restrict__ pavg,
    const float* __restrict__ pmax, const float* __restrict__ conv_w,
    short* __restrict__ ybuf)
{
  int tok = blockIdx.x * 4 + (threadIdx.x >> 6);
  int lane = threadIdx.x & 63;
  int b = tok >> 12, s = tok & 4095;

  // global attention weights (qg is bf16 in qkvb cols [1536,1664))
  const short* qr = &qkvb[(size_t)tok * QKVS + 1536];
  const float* kb_ = &kg[b * 512];
  float p0 = 0.f, p1 = 0.f, p2 = 0.f, p3 = 0.f;
  for (int d = lane; d < 128; d += 64) {
    float q = bf2f(qr[d]);
    p0 += q * kb_[d];
    p1 += q * kb_[128 + d];
    p2 += q * kb_[256 + d];
    p3 += q * kb_[384 + d];
  }
#pragma unroll
  for (int off = 32; off; off >>= 1) {
    p0 += __shfl_xor(p0, off); p1 += __shfl_xor(p1, off);
    p2 += __shfl_xor(p2, off); p3 += __shfl_xor(p3, off);
  }
  const float gs = 0.08838834764831845f;  // 1/sqrt(128)
  p0 *= gs; p1 *= gs; p2 *= gs; p3 *= gs;
  float mx = fmaxf(fmaxf(p0, p1), fmaxf(p2, p3));
  float e0 = __expf(p0 - mx), e1 = __expf(p1 - mx), e2 = __expf(p2 - mx), e3 = __expf(p3 - mx);
  float inv = 1.0f / (e0 + e1 + e2 + e3);
  e0 *= inv; e1 *= inv; e2 *= inv; e3 *= inv;

  // conv gate (zero-padded width-7, channels {avg,max})
  float g = 0.f;
#pragma unroll
  for (int tk = 0; tk < 7; tk++) {
    int ss = s + tk - 3;
    if (ss >= 0 && ss < SS) {
      g += conv_w[tk] * pavg[b * SS + ss] + conv_w[7 + tk] * pmax[b * SS + ss];
    }
  }
  g = 1.0f / (1.0f + __expf(-g));

  const short* xr = &xb[(size_t)tok * CC];
  const float* k0r = &kgo[b * 2048];
  short* yr = &ybuf[(size_t)tok * CC];
  for (int c = lane; c < CC; c += 64) {
    float xl = bf2f(yr[c]);
    float xg = e0 * k0r[c] + e1 * k0r[512 + c] + e2 * k0r[1024 + c] + e3 * k0r[1536 + c] + bgo[c];
    yr[c] = f2bf((bf2f(xr[c]) + xl + xg) * g);
  }
}

// ---------------- launcher ----------------
extern "C" void kernel_launch(void* const* d_in, const int* in_sizes, int n_in,
                              void* d_out, int out_size, void* d_ws, size_t ws_size,
                              hipStream_t stream)
{
  const float* x     = (const float*)d_in[0];
  const float* Wq    = (const float*)d_in[1];
  const float* bq    = (const float*)d_in[2];
  const float* Wk    = (const float*)d_in[3];
  const float* bk    = (const float*)d_in[4];
  const float* Wv    = (const float*)d_in[5];
  const float* bv    = (const float*)d_in[6];
  const float* Wo    = (const float*)d_in[7];
  const float* bo    = (const float*)d_in[8];
  const float* Wg    = (const float*)d_in[9];
  const float* bg    = (const float*)d_in[10];
  const float* Wgo   = (const float*)d_in[11];
  const float* bgo   = (const float*)d_in[12];
  const float* convw = (const float*)d_in[13];
  float* out = (float*)d_out;

  char* ws = (char*)d_ws;
  size_t off = 0;
  auto alloc = [&](size_t bytes) -> void* {
    void* p = ws + off;
    off += (bytes + 255) & ~(size_t)255;
    return p;
  };
  short* xb    = (short*)alloc((size_t)NTOK * CC * 2);           // 33.5 MB
  short* qkvb  = (short*)alloc((size_t)NTOK * QKVS * 2);         // 109 MB
  short* WtQKV = (short*)alloc((size_t)QKVS * 512 * 2);          // [q|k|v|WqWg] rows
  short* WtO   = (short*)alloc((size_t)512 * 512 * 2);
  short* WtG   = (short*)alloc((size_t)128 * 512 * 2);
  short* Wqb   = (short*)alloc((size_t)512 * 512 * 2);
  float* bqkv  = (float*)alloc(QKVS * 4);
  float* zb    = (float*)alloc(512 * 4);                         // FULL 512 zero bias
  float* kg    = (float*)alloc(8 * 4 * 128 * 4);
  float* kgo   = (float*)alloc(8 * 4 * 512 * 4);
  float* pavg  = (float*)alloc((size_t)NTOK * 4);
  float* pmax  = (float*)alloc((size_t)NTOK * 4);
  short* ybuf  = (short*)alloc((size_t)NTOK * CC * 2);           // 33.5 MB (xl then y)
  short* WtQG  = WtQKV + (size_t)1536 * 512;                     // tail rows of WtQKV

  prep_weights<<<3072, 256, 0, stream>>>(Wq, Wk, Wv, Wo, Wg, bq, bk, bv, bg,
                                         WtQKV, WtO, WtG, Wqb, bqkv, zb);
  cast_pool_kernel<<<NTOK / 4, 256, 0, stream>>>(x, xb, pavg, pmax);

  // WtQG[n][c] = (Wq@Wg)[c][n]:  M=128 (n), N=512 (c), K=512, A=WtG, Wt=Wqb
  gemm_kernel<1><<<dim3(4, 1), 256, 0, stream>>>(WtG, 512, Wqb, zb, WtQG, 512, 512);

  // qkv|qg = x @ [Wq|Wk|Wv|WqWg] + [bq|bk|bv|bqg]  (M=32768, N=1664, K=512), bf16
  gemm_kernel<1><<<dim3(13, 256), 256, 0, stream>>>(xb, CC, WtQKV, bqkv, qkvb, QKVS, CC);

  winattn_kernel<<<NTOK / 32, 256, 0, stream>>>(qkvb, ybuf);

  kg_kernel<<<16, 256, 0, stream>>>(x, Wg, bg, kg);
  kgo_kernel<<<32, 256, 0, stream>>>(kg, Wgo, kgo);

  combine_kernel<<<NTOK / 4, 256, 0, stream>>>(xb, qkvb, kg, kgo, bgo, pavg, pmax, convw, ybuf);

  // out = y @ Wo + bo  (M=32768, N=512, K=512), fp32 out
  gemm_kernel<0><<<dim3(4, 256), 256, 0, stream>>>(ybuf, CC, WtO, bo, out, CC, CC);
}

// Round 6
// 239.188 us; speedup vs baseline: 1.1727x; 1.1727x over previous
//
#include <hip/hip_runtime.h>
#include <hip/hip_bf16.h>

#define BB 8
#define SS 4096
#define CC 512
#define NTOK (BB*SS)   // 32768
#define QKVS 1664      // q(512) | k(512) | v(512) | qg(128)

typedef __attribute__((ext_vector_type(8))) short bf16x8;
typedef __attribute__((ext_vector_type(4))) float f32x4;
typedef __attribute__((ext_vector_type(4))) short s16x4;

__device__ __forceinline__ float bf2f(short s) {
  return __uint_as_float(((unsigned)(unsigned short)s) << 16);
}
__device__ __forceinline__ short f2bf(float f) {
  __hip_bfloat16 h = __float2bfloat16(f);
  return *reinterpret_cast<short*>(&h);
}

__device__ __forceinline__ f32x4 pv_mfma(s16x4 a, s16x4 b, f32x4 c) {
#if __has_builtin(__builtin_amdgcn_mfma_f32_16x16x16bf16_1k)
  return __builtin_amdgcn_mfma_f32_16x16x16bf16_1k(a, b, c, 0, 0, 0);
#else
  f32x4 d;
  asm volatile("v_mfma_f32_16x16x16_bf16 %0, %1, %2, %3\n\ts_nop 7\n\ts_nop 7"
               : "=v"(d) : "v"(a), "v"(b), "v"(c));
  return d;
#endif
}

// async global -> LDS, 16B per lane; LDS dest is wave-uniform base + lane*16
__device__ __forceinline__ void gload_lds16(const short* g, short* l) {
  __builtin_amdgcn_global_load_lds(
      (const __attribute__((address_space(1))) unsigned int*)g,
      (__attribute__((address_space(3))) unsigned int*)l, 16, 0, 0);
}

// ---------------- prep: transpose+cast weights, bias concat, bqg, zero bias ----------------
__global__ __launch_bounds__(256) void prep_weights(
    const float* __restrict__ Wq, const float* __restrict__ Wk, const float* __restrict__ Wv,
    const float* __restrict__ Wo, const float* __restrict__ Wg,
    const float* __restrict__ bq, const float* __restrict__ bk, const float* __restrict__ bv,
    const float* __restrict__ bg,
    short* __restrict__ WtQKV, short* __restrict__ WtO, short* __restrict__ WtG,
    short* __restrict__ Wqb, float* __restrict__ bqkv, float* __restrict__ zb)
{
  int i = blockIdx.x * 256 + threadIdx.x;
  if (i < 1536 * 512) {                  // WtQKV[n][k] = W*(k, n%512)
    int n = i >> 9, k = i & 511;
    const float* W = (n < 512) ? Wq : (n < 1024) ? Wk : Wv;
    WtQKV[i] = f2bf(W[k * 512 + (n & 511)]);
  }
  if (i < 512 * 512) {                   // WtO[n][k] = Wo[k][n];  Wqb = bf16(Wq) row-major
    int n = i >> 9, k = i & 511;
    WtO[i] = f2bf(Wo[k * 512 + n]);
    Wqb[i] = f2bf(Wq[i]);
  }
  if (i < 128 * 512) {                   // WtG[n][k] = Wg[k][n]
    int n = i >> 9, k = i & 511;
    WtG[i] = f2bf(Wg[k * 128 + n]);
  }
  if (i < 1536) {
    bqkv[i] = (i < 512) ? bq[i] : (i < 1024) ? bk[i - 512] : bv[i - 1024];
  }
  if (i < 512) zb[i] = 0.f;              // zero bias — FULL 512 cols (fold GEMM N=512)
  if (i < 128) {                         // bqg[n] = bg[n] + sum_c bq[c]*Wg[c][n]
    float s = bg[i];
    for (int c = 0; c < 512; c++) s += bq[c] * Wg[c * 128 + i];
    bqkv[1536 + i] = s;
  }
}

// ---------------- fused: cast x fp32->bf16 + channel pool (avg,max) ----------------
__global__ __launch_bounds__(256) void cast_pool_kernel(const float* __restrict__ x,
                                                        short* __restrict__ xb,
                                                        float* __restrict__ pavg,
                                                        float* __restrict__ pmax)
{
  int tok = blockIdx.x * 4 + (threadIdx.x >> 6);
  int lane = threadIdx.x & 63;
  const float* xr = &x[(size_t)tok * CC];
  float4 a = *(const float4*)&xr[lane * 4];
  float4 b = *(const float4*)&xr[256 + lane * 4];
  s16x4 oa, ob;
  oa[0] = f2bf(a.x); oa[1] = f2bf(a.y); oa[2] = f2bf(a.z); oa[3] = f2bf(a.w);
  ob[0] = f2bf(b.x); ob[1] = f2bf(b.y); ob[2] = f2bf(b.z); ob[3] = f2bf(b.w);
  *(s16x4*)&xb[(size_t)tok * CC + lane * 4] = oa;
  *(s16x4*)&xb[(size_t)tok * CC + 256 + lane * 4] = ob;
  float s = (a.x + a.y) + (a.z + a.w) + (b.x + b.y) + (b.z + b.w);
  float m = fmaxf(fmaxf(fmaxf(a.x, a.y), fmaxf(a.z, a.w)),
                  fmaxf(fmaxf(b.x, b.y), fmaxf(b.z, b.w)));
#pragma unroll
  for (int off = 32; off; off >>= 1) {
    s += __shfl_down(s, off);
    m = fmaxf(m, __shfl_down(m, off));
  }
  if (lane == 0) { pavg[tok] = s * (1.0f / CC); pmax[tok] = m; }
}

// ---------------- bf16 MFMA GEMM (m97 single-buffer, K=512 unrolled) ----------------
// C[M,N] = A[M,K=512] @ Wt[N,512]^T + bias. tile 128x128, 4 waves (2x2), wave 64x64, BK=32.
// 1-D grid (nwg blocks); SWZ: XCD-aware remap (requires nwg % 8 == 0).
template<int OUT_BF16, int SWZ>
__global__ __launch_bounds__(256, 3) void gemm_kernel(
    const short* __restrict__ A, int lda,
    const short* __restrict__ Wt,
    const float* __restrict__ bias,
    void* __restrict__ Cp, int ldc, int nx)
{
  __shared__ short As[128 * 32];
  __shared__ short Bs[128 * 32];
  int id = blockIdx.x;
  if (SWZ) {                              // T1: contiguous tile chunk per XCD
    const int cpx = gridDim.x >> 3;
    id = (id & 7) * cpx + (id >> 3);
  }
  const int n0 = (id % nx) * 128;
  const int m0 = (id / nx) * 128;
  const int t = threadIdx.x;
  const int lane = t & 63, w = t >> 6;
  const int wm = (w >> 1) * 64, wn = (w & 1) * 64;
  const int lr = lane & 15, kb = (lane >> 4) * 8;

  // staging: lane covers row (w*16 + lane/4), elems (lane%4)*8
  const int srow = w * 16 + (lane >> 2);
  const int scol = (lane & 3) * 8;
  const short* Ag0 = A + (size_t)(m0 + srow) * lda + scol;
  const short* Ag1 = Ag0 + (size_t)64 * lda;
  const short* Bg0 = Wt + (size_t)(n0 + srow) * 512 + scol;
  const short* Bg1 = Bg0 + (size_t)64 * 512;
  short* Al0 = &As[(w * 16) * 32];
  short* Al1 = &As[(64 + w * 16) * 32];
  short* Bl0 = &Bs[(w * 16) * 32];
  short* Bl1 = &Bs[(64 + w * 16) * 32];

  f32x4 acc[4][4];
#pragma unroll
  for (int i = 0; i < 4; i++)
#pragma unroll
    for (int j = 0; j < 4; j++) acc[i][j] = (f32x4){0.f, 0.f, 0.f, 0.f};

#pragma unroll
  for (int k0 = 0; k0 < 512; k0 += 32) {
    gload_lds16(Ag0 + k0, Al0);
    gload_lds16(Ag1 + k0, Al1);
    gload_lds16(Bg0 + k0, Bl0);
    gload_lds16(Bg1 + k0, Bl1);
    __syncthreads();                     // implicit vmcnt(0) drain
    bf16x8 af[4], bfr[4];
#pragma unroll
    for (int mt = 0; mt < 4; mt++) af[mt]  = *(bf16x8*)&As[(wm + mt * 16 + lr) * 32 + kb];
#pragma unroll
    for (int nt = 0; nt < 4; nt++) bfr[nt] = *(bf16x8*)&Bs[(wn + nt * 16 + lr) * 32 + kb];
#pragma unroll
    for (int mt = 0; mt < 4; mt++)
#pragma unroll
      for (int nt = 0; nt < 4; nt++)
        acc[mt][nt] = __builtin_amdgcn_mfma_f32_16x16x32_bf16(af[mt], bfr[nt], acc[mt][nt], 0, 0, 0);
    __syncthreads();
  }

  // epilogue: D mapping col=lane&15, row=(lane>>4)*4+j
  const int cr = (lane >> 4) * 4;
#pragma unroll
  for (int nt = 0; nt < 4; nt++) {
    int col = n0 + wn + nt * 16 + lr;
    float bv = bias[col];
#pragma unroll
    for (int mt = 0; mt < 4; mt++) {
      int row = m0 + wm + mt * 16 + cr;
#pragma unroll
      for (int j = 0; j < 4; j++) {
        float v = acc[mt][nt][j] + bv;
        if (OUT_BF16) ((short*)Cp)[(size_t)(row + j) * ldc + col] = f2bf(v);
        else          ((float*)Cp)[(size_t)(row + j) * ldc + col] = v;
      }
    }
  }
}

// ---------------- windowed attention: MFMA, no LDS ----------------
// Block = 4 waves; 2 windows per block; wave w: window w>>1, col-half w&1.
// Swapped QK^T (A=K, B=Q) -> lane holds S[q=lane&15][key=(lane>>4)*4+jj]; softmax is
// 2x shfl_xor; P lands exactly in the 16x16x16 A-operand layout for PV.
__global__ __launch_bounds__(256) void winattn_kernel(const short* __restrict__ qkvb,
                                                      short* __restrict__ xl)
{
  const int t = threadIdx.x;
  const int lane = t & 63, w = t >> 6;
  const int t0 = (blockIdx.x * 2 + (w >> 1)) * 16;   // window token base
  const int half = w & 1;                            // col half

  const int qrow = lane & 15;
  const int grp8 = (lane >> 4) * 8;
  const int krow = (lane >> 4) * 4;

  const short* kqbase = &qkvb[(size_t)(t0 + qrow) * QKVS];
  f32x4 acc = (f32x4){0.f, 0.f, 0.f, 0.f};
#pragma unroll
  for (int k0 = 0; k0 < 512; k0 += 32) {
    bf16x8 kf = *(const bf16x8*)&kqbase[512 + k0 + grp8];
    bf16x8 qf = *(const bf16x8*)&kqbase[k0 + grp8];
    acc = __builtin_amdgcn_mfma_f32_16x16x32_bf16(kf, qf, acc, 0, 0, 0);
  }

  const float scale = 0.04419417382415922f;  // 1/sqrt(512)
  float s0 = acc[0] * scale, s1 = acc[1] * scale, s2 = acc[2] * scale, s3 = acc[3] * scale;
  float m = fmaxf(fmaxf(s0, s1), fmaxf(s2, s3));
  m = fmaxf(m, __shfl_xor(m, 16));
  m = fmaxf(m, __shfl_xor(m, 32));
  float e0 = __expf(s0 - m), e1 = __expf(s1 - m), e2 = __expf(s2 - m), e3 = __expf(s3 - m);
  float sum = e0 + e1 + e2 + e3;
  sum += __shfl_xor(sum, 16);
  sum += __shfl_xor(sum, 32);
  float inv = 1.0f / sum;
  s16x4 pa;
  pa[0] = f2bf(e0 * inv); pa[1] = f2bf(e1 * inv);
  pa[2] = f2bf(e2 * inv); pa[3] = f2bf(e3 * inv);

  const short* vbase = &qkvb[(size_t)t0 * QKVS + 1024];
  const int colo = lane & 15;
#pragma unroll
  for (int ct = 0; ct < 16; ct++) {
    const int c0 = half * 256 + ct * 16;
    s16x4 bf;
#pragma unroll
    for (int u = 0; u < 4; u++)
      bf[u] = vbase[(size_t)(krow + u) * QKVS + c0 + colo];
    f32x4 d = pv_mfma(pa, bf, (f32x4){0.f, 0.f, 0.f, 0.f});
#pragma unroll
    for (int jj = 0; jj < 4; jj++)
      xl[(size_t)(t0 + krow + jj) * 512 + c0 + colo] = f2bf(d[jj]);
  }
}

// ---------------- fused kg+kgo: one block per (b,g) ----------------
// phase1: kg[b][g][d] = x[b,gidx[g],:] @ Wg + bg   (fp32, 128 threads)
// phase2: kgo[b][g][c] = kg[b][g][:] @ Wgo          (256 threads, 2 cols each)
__global__ __launch_bounds__(256) void kg_kgo_kernel(const float* __restrict__ x,
                                                     const float* __restrict__ Wg,
                                                     const float* __restrict__ bg,
                                                     const float* __restrict__ Wgo,
                                                     float* __restrict__ kg,
                                                     float* __restrict__ kgo)
{
  __shared__ float kr[128];
  const int bg_ = blockIdx.x;           // 0..31  (b = bg_>>2, g = bg_&3)
  const int b = bg_ >> 2, g = bg_ & 3;
  const int gidx[4] = {0, 1365, 2730, 4095};
  const int t = threadIdx.x;
  const float* xr = &x[((size_t)b * SS + gidx[g]) * CC];
  if (t < 128) {
    float s = bg[t];
    for (int c = 0; c < CC; c++) s += xr[c] * Wg[c * 128 + t];
    kr[t] = s;
    kg[bg_ * 128 + t] = s;
  }
  __syncthreads();
  for (int c = t; c < 512; c += 256) {
    float s = 0.f;
    for (int d = 0; d < 128; d++) s += kr[d] * Wgo[d * 512 + c];
    kgo[bg_ * 512 + c] = s;
  }
}

// ---------------- combine: gattn softmax + conv gate + y = (x+xl+xg)*gate (bf16) ----------------
__global__ __launch_bounds__(256) void combine_kernel(
    const short* __restrict__ xb, const short* __restrict__ qkvb,
    const float* __restrict__ kg, const float* __restrict__ kgo,
    const float* __restrict__ bgo, const float* __restrict__ pavg,
    const float* __restrict__ pmax, const float* __restrict__ conv_w,
    short* __restrict__ ybuf)
{
  int tok = blockIdx.x * 4 + (threadIdx.x >> 6);
  int lane = threadIdx.x & 63;
  int b = tok >> 12, s = tok & 4095;

  // global attention weights (qg is bf16 in qkvb cols [1536,1664))
  const short* qr = &qkvb[(size_t)tok * QKVS + 1536];
  const float* kb_ = &kg[b * 512];
  float p0 = 0.f, p1 = 0.f, p2 = 0.f, p3 = 0.f;
  {
    bf16x8 qv = *(const bf16x8*)&qr[(lane & 15) * 8];   // 16 lanes cover 128 dims
#pragma unroll
    for (int u = 0; u < 8; u++) {
      int d = (lane & 15) * 8 + u;
      float q = bf2f(qv[u]);
      p0 += q * kb_[d];
      p1 += q * kb_[128 + d];
      p2 += q * kb_[256 + d];
      p3 += q * kb_[384 + d];
    }
  }
#pragma unroll
  for (int off = 8; off; off >>= 1) {     // reduce within 16-lane groups
    p0 += __shfl_xor(p0, off); p1 += __shfl_xor(p1, off);
    p2 += __shfl_xor(p2, off); p3 += __shfl_xor(p3, off);
  }
  const float gs = 0.08838834764831845f;  // 1/sqrt(128)
  p0 *= gs; p1 *= gs; p2 *= gs; p3 *= gs;
  float mx = fmaxf(fmaxf(p0, p1), fmaxf(p2, p3));
  float e0 = __expf(p0 - mx), e1 = __expf(p1 - mx), e2 = __expf(p2 - mx), e3 = __expf(p3 - mx);
  float inv = 1.0f / (e0 + e1 + e2 + e3);
  e0 *= inv; e1 *= inv; e2 *= inv; e3 *= inv;

  // conv gate (zero-padded width-7, channels {avg,max})
  float g = 0.f;
#pragma unroll
  for (int tk = 0; tk < 7; tk++) {
    int ss = s + tk - 3;
    if (ss >= 0 && ss < SS) {
      g += conv_w[tk] * pavg[b * SS + ss] + conv_w[7 + tk] * pmax[b * SS + ss];
    }
  }
  g = 1.0f / (1.0f + __expf(-g));

  // vectorized: lane handles cols [lane*8, lane*8+8)
  const int c0 = lane * 8;
  const short* xr = &xb[(size_t)tok * CC + c0];
  const float* k0r = &kgo[b * 2048];
  short* yr = &ybuf[(size_t)tok * CC + c0];
  bf16x8 xlv = *(const bf16x8*)yr;
  bf16x8 xv  = *(const bf16x8*)xr;
  bf16x8 ov;
#pragma unroll
  for (int u = 0; u < 8; u++) {
    int c = c0 + u;
    float xg = e0 * k0r[c] + e1 * k0r[512 + c] + e2 * k0r[1024 + c] + e3 * k0r[1536 + c] + bgo[c];
    ov[u] = f2bf((bf2f(xv[u]) + bf2f(xlv[u]) + xg) * g);
  }
  *(bf16x8*)yr = ov;
}

// ---------------- launcher ----------------
extern "C" void kernel_launch(void* const* d_in, const int* in_sizes, int n_in,
                              void* d_out, int out_size, void* d_ws, size_t ws_size,
                              hipStream_t stream)
{
  const float* x     = (const float*)d_in[0];
  const float* Wq    = (const float*)d_in[1];
  const float* bq    = (const float*)d_in[2];
  const float* Wk    = (const float*)d_in[3];
  const float* bk    = (const float*)d_in[4];
  const float* Wv    = (const float*)d_in[5];
  const float* bv    = (const float*)d_in[6];
  const float* Wo    = (const float*)d_in[7];
  const float* bo    = (const float*)d_in[8];
  const float* Wg    = (const float*)d_in[9];
  const float* bg    = (const float*)d_in[10];
  const float* Wgo   = (const float*)d_in[11];
  const float* bgo   = (const float*)d_in[12];
  const float* convw = (const float*)d_in[13];
  float* out = (float*)d_out;

  char* ws = (char*)d_ws;
  size_t off = 0;
  auto alloc = [&](size_t bytes) -> void* {
    void* p = ws + off;
    off += (bytes + 255) & ~(size_t)255;
    return p;
  };
  short* xb    = (short*)alloc((size_t)NTOK * CC * 2);           // 33.5 MB
  short* qkvb  = (short*)alloc((size_t)NTOK * QKVS * 2);         // 109 MB
  short* WtQKV = (short*)alloc((size_t)QKVS * 512 * 2);          // [q|k|v|WqWg] rows
  short* WtO   = (short*)alloc((size_t)512 * 512 * 2);
  short* WtG   = (short*)alloc((size_t)128 * 512 * 2);
  short* Wqb   = (short*)alloc((size_t)512 * 512 * 2);
  float* bqkv  = (float*)alloc(QKVS * 4);
  float* zb    = (float*)alloc(512 * 4);                         // FULL 512 zero bias
  float* kg    = (float*)alloc(8 * 4 * 128 * 4);
  float* kgo   = (float*)alloc(8 * 4 * 512 * 4);
  float* pavg  = (float*)alloc((size_t)NTOK * 4);
  float* pmax  = (float*)alloc((size_t)NTOK * 4);
  short* ybuf  = (short*)alloc((size_t)NTOK * CC * 2);           // 33.5 MB (xl then y)
  short* WtQG  = WtQKV + (size_t)1536 * 512;                     // tail rows of WtQKV

  prep_weights<<<3072, 256, 0, stream>>>(Wq, Wk, Wv, Wo, Wg, bq, bk, bv, bg,
                                         WtQKV, WtO, WtG, Wqb, bqkv, zb);
  cast_pool_kernel<<<NTOK / 4, 256, 0, stream>>>(x, xb, pavg, pmax);

  // WtQG[n][c] = (Wq@Wg)[c][n]:  nwg=4 (nx=4, one m-tile), no swizzle
  gemm_kernel<1, 0><<<4, 256, 0, stream>>>(WtG, 512, Wqb, zb, WtQG, 512, 4);

  // qkv|qg = x @ [Wq|Wk|Wv|WqWg] + [bq|bk|bv|bqg]  (M=32768, N=1664), nwg=3328
  gemm_kernel<1, 1><<<13 * 256, 256, 0, stream>>>(xb, CC, WtQKV, bqkv, qkvb, QKVS, 13);

  winattn_kernel<<<NTOK / 32, 256, 0, stream>>>(qkvb, ybuf);

  kg_kgo_kernel<<<32, 256, 0, stream>>>(x, Wg, bg, Wgo, kg, kgo);

  combine_kernel<<<NTOK / 4, 256, 0, stream>>>(xb, qkvb, kg, kgo, bgo, pavg, pmax, convw, ybuf);

  // out = y @ Wo + bo  (M=32768, N=512, fp32 out), nwg=1024
  gemm_kernel<0, 1><<<4 * 256, 256, 0, stream>>>(ybuf, CC, WtO, bo, out, CC, 4);
}

// Round 7
// 238.247 us; speedup vs baseline: 1.1773x; 1.0039x over previous
//
#include <hip/hip_runtime.h>
#include <hip/hip_bf16.h>

#define BB 8
#define SS 4096
#define CC 512
#define NTOK (BB*SS)   // 32768
#define QKVS 1664      // q(512) | k(512) | v(512) | qg(128)

typedef __attribute__((ext_vector_type(8))) short bf16x8;
typedef __attribute__((ext_vector_type(4))) float f32x4;
typedef __attribute__((ext_vector_type(4))) short s16x4;

__device__ __forceinline__ float bf2f(short s) {
  return __uint_as_float(((unsigned)(unsigned short)s) << 16);
}
__device__ __forceinline__ short f2bf(float f) {
  __hip_bfloat16 h = __float2bfloat16(f);
  return *reinterpret_cast<short*>(&h);
}

__device__ __forceinline__ f32x4 pv_mfma(s16x4 a, s16x4 b, f32x4 c) {
#if __has_builtin(__builtin_amdgcn_mfma_f32_16x16x16bf16_1k)
  return __builtin_amdgcn_mfma_f32_16x16x16bf16_1k(a, b, c, 0, 0, 0);
#else
  f32x4 d;
  asm volatile("v_mfma_f32_16x16x16_bf16 %0, %1, %2, %3\n\ts_nop 7\n\ts_nop 7"
               : "=v"(d) : "v"(a), "v"(b), "v"(c));
  return d;
#endif
}

// async global -> LDS, 16B per lane; LDS dest is wave-uniform base + lane*16
__device__ __forceinline__ void gload_lds16(const short* g, short* l) {
  __builtin_amdgcn_global_load_lds(
      (const __attribute__((address_space(1))) unsigned int*)g,
      (__attribute__((address_space(3))) unsigned int*)l, 16, 0, 0);
}

// ---------------- prep: transpose+cast weights, bias concat, bqg, zero bias ----------------
__global__ __launch_bounds__(256) void prep_weights(
    const float* __restrict__ Wq, const float* __restrict__ Wk, const float* __restrict__ Wv,
    const float* __restrict__ Wo, const float* __restrict__ Wg,
    const float* __restrict__ bq, const float* __restrict__ bk, const float* __restrict__ bv,
    const float* __restrict__ bg,
    short* __restrict__ WtQKV, short* __restrict__ WtO, short* __restrict__ WtG,
    short* __restrict__ Wqb, float* __restrict__ bqkv, float* __restrict__ zb)
{
  int i = blockIdx.x * 256 + threadIdx.x;
  if (i < 1536 * 512) {                  // WtQKV[n][k] = W*(k, n%512)
    int n = i >> 9, k = i & 511;
    const float* W = (n < 512) ? Wq : (n < 1024) ? Wk : Wv;
    WtQKV[i] = f2bf(W[k * 512 + (n & 511)]);
  }
  if (i < 512 * 512) {                   // WtO[n][k] = Wo[k][n];  Wqb = bf16(Wq) row-major
    int n = i >> 9, k = i & 511;
    WtO[i] = f2bf(Wo[k * 512 + n]);
    Wqb[i] = f2bf(Wq[i]);
  }
  if (i < 128 * 512) {                   // WtG[n][k] = Wg[k][n]
    int n = i >> 9, k = i & 511;
    WtG[i] = f2bf(Wg[k * 128 + n]);
  }
  if (i < 1536) {
    bqkv[i] = (i < 512) ? bq[i] : (i < 1024) ? bk[i - 512] : bv[i - 1024];
  }
  if (i < 512) zb[i] = 0.f;              // zero bias — FULL 512 cols (fold GEMM N=512)
  if (i < 128) {                         // bqg[n] = bg[n] + sum_c bq[c]*Wg[c][n]
    float s = bg[i];
    for (int c = 0; c < 512; c++) s += bq[c] * Wg[c * 128 + i];
    bqkv[1536 + i] = s;
  }
}

// ---------------- fused: cast x fp32->bf16 + channel pool (avg,max) ----------------
__global__ __launch_bounds__(256) void cast_pool_kernel(const float* __restrict__ x,
                                                        short* __restrict__ xb,
                                                        float* __restrict__ pavg,
                                                        float* __restrict__ pmax)
{
  int tok = blockIdx.x * 4 + (threadIdx.x >> 6);
  int lane = threadIdx.x & 63;
  const float* xr = &x[(size_t)tok * CC];
  float4 a = *(const float4*)&xr[lane * 4];
  float4 b = *(const float4*)&xr[256 + lane * 4];
  s16x4 oa, ob;
  oa[0] = f2bf(a.x); oa[1] = f2bf(a.y); oa[2] = f2bf(a.z); oa[3] = f2bf(a.w);
  ob[0] = f2bf(b.x); ob[1] = f2bf(b.y); ob[2] = f2bf(b.z); ob[3] = f2bf(b.w);
  *(s16x4*)&xb[(size_t)tok * CC + lane * 4] = oa;
  *(s16x4*)&xb[(size_t)tok * CC + 256 + lane * 4] = ob;
  float s = (a.x + a.y) + (a.z + a.w) + (b.x + b.y) + (b.z + b.w);
  float m = fmaxf(fmaxf(fmaxf(a.x, a.y), fmaxf(a.z, a.w)),
                  fmaxf(fmaxf(b.x, b.y), fmaxf(b.z, b.w)));
#pragma unroll
  for (int off = 32; off; off >>= 1) {
    s += __shfl_down(s, off);
    m = fmaxf(m, __shfl_down(m, off));
  }
  if (lane == 0) { pavg[tok] = s * (1.0f / CC); pmax[tok] = m; }
}

// ---------------- bf16 MFMA GEMM, BK=64 single-buffer, XOR-swizzled LDS ----------------
// C[M,N] = A[M,512] @ Wt[N,512]^T + bias (A/Wt row stride fixed 512).
// tile 128x128, 4 waves (2x2), wave 64x64. LDS rows are 128B -> 32-way conflict if linear;
// fix: both-sides involution (rule 21): source col slot ^= (row&7), reader slot ^= (row&7).
template<int OUT_BF16, int SWZ>
__global__ __launch_bounds__(256, 3) void gemm_kernel(
    const short* __restrict__ A,
    const short* __restrict__ Wt,
    const float* __restrict__ bias,
    void* __restrict__ Cp, int ldc, int nx)
{
  __shared__ short As[128 * 64];
  __shared__ short Bs[128 * 64];
  int id = blockIdx.x;
  if (SWZ) {                              // T1: contiguous tile chunk per XCD (grid%8==0)
    const int cpx = gridDim.x >> 3;
    id = (id & 7) * cpx + (id >> 3);
  }
  const int n0 = (id % nx) * 128;
  const int m0 = (id / nx) * 128;
  const int t = threadIdx.x;
  const int lane = t & 63, w = t >> 6;
  const int wm = (w >> 1) * 64, wn = (w & 1) * 64;
  const int lr = lane & 15;
  const int g8b = (lane >> 4) * 16;       // byte offset of k-frag (8 bf16)
  const int xorb = (lr & 7) << 4;         // reader swizzle (row&7)<<4 bytes

  // staging: per sub-stage s, wave w covers rows s*32 + w*8 + (lane>>3), 16B per lane.
  // source col slot pre-XORed with (row&7)==(lane>>3) so linear LDS dest holds swizzled data.
  const int srow = w * 8 + (lane >> 3);
  const int scol = (((lane & 7) ^ (lane >> 3)) << 4) >> 1;    // elems
  const short* Ag = A + (size_t)(m0 + srow) * 512 + scol;
  const short* Bg = Wt + (size_t)(n0 + srow) * 512 + scol;
  short* Al = &As[(w * 8) * 64];
  short* Bl = &Bs[(w * 8) * 64];

  f32x4 acc[4][4];
#pragma unroll
  for (int i = 0; i < 4; i++)
#pragma unroll
    for (int j = 0; j < 4; j++) acc[i][j] = (f32x4){0.f, 0.f, 0.f, 0.f};

  for (int k0 = 0; k0 < 512; k0 += 64) {
#pragma unroll
    for (int s = 0; s < 4; s++) {
      gload_lds16(Ag + k0 + s * (32 * 512), Al + s * (32 * 64));
      gload_lds16(Bg + k0 + s * (32 * 512), Bl + s * (32 * 64));
    }
    __syncthreads();                     // implicit vmcnt(0) drain
#pragma unroll
    for (int kk = 0; kk < 2; kk++) {
      bf16x8 af[4], bfr[4];
      const int ko = ((kk * 64 + g8b) ^ xorb) >> 1;   // swizzled elem offset in row
#pragma unroll
      for (int mt = 0; mt < 4; mt++) af[mt]  = *(bf16x8*)&As[(wm + mt * 16 + lr) * 64 + ko];
#pragma unroll
      for (int nt = 0; nt < 4; nt++) bfr[nt] = *(bf16x8*)&Bs[(wn + nt * 16 + lr) * 64 + ko];
#pragma unroll
      for (int mt = 0; mt < 4; mt++)
#pragma unroll
        for (int nt = 0; nt < 4; nt++)
          acc[mt][nt] = __builtin_amdgcn_mfma_f32_16x16x32_bf16(af[mt], bfr[nt], acc[mt][nt], 0, 0, 0);
    }
    __syncthreads();
  }

  // epilogue: D mapping col=lane&15, row=(lane>>4)*4+j
  const int cr = (lane >> 4) * 4;
#pragma unroll
  for (int nt = 0; nt < 4; nt++) {
    int col = n0 + wn + nt * 16 + lr;
    float bv = bias[col];
#pragma unroll
    for (int mt = 0; mt < 4; mt++) {
      int row = m0 + wm + mt * 16 + cr;
#pragma unroll
      for (int j = 0; j < 4; j++) {
        float v = acc[mt][nt][j] + bv;
        if (OUT_BF16) ((short*)Cp)[(size_t)(row + j) * ldc + col] = f2bf(v);
        else          ((float*)Cp)[(size_t)(row + j) * ldc + col] = v;
      }
    }
  }
}

// ---------------- fused windowed attention + combine ----------------
// Block = 4 waves, 2 windows (32 tokens). Phase 0: per-token gattn softmax (qg.kg) and
// conv gate -> LDS. Then swapped-QK^T MFMA attention (as before); PV epilogue applies
// y = (x + xl + xg) * gate directly and writes final y (no xl round-trip).
__global__ __launch_bounds__(256) void winattn_combine_kernel(
    const short* __restrict__ qkvb, const short* __restrict__ xb,
    const float* __restrict__ kg, const float* __restrict__ kgo,
    const float* __restrict__ bgo, const float* __restrict__ pavg,
    const float* __restrict__ pmax, const float* __restrict__ conv_w,
    short* __restrict__ y)
{
  __shared__ float scs[32][4];
  __shared__ float4 esm[32];
  __shared__ float gateb[32];
  const int t = threadIdx.x;
  const int t0b = blockIdx.x * 32;            // block token base
  const int bb = t0b >> 12;                   // batch (32 | 4096)

  // ---- phase 0a: raw gattn scores (4 threads per token) ----
  if (t < 128) {
    const int tl = t >> 2, gi = t & 3;
    const short* qr = &qkvb[(size_t)(t0b + tl) * QKVS + 1536];
    const float* kr = &kg[bb * 512 + gi * 128];
    float s = 0.f;
    for (int d0 = 0; d0 < 128; d0 += 8) {
      bf16x8 qv = *(const bf16x8*)&qr[d0];
#pragma unroll
      for (int u = 0; u < 8; u++) s += bf2f(qv[u]) * kr[d0 + u];
    }
    scs[tl][gi] = s * 0.08838834764831845f;   // 1/sqrt(128)
  }
  __syncthreads();
  // ---- phase 0b: softmax + conv gate (1 thread per token) ----
  if (t < 32) {
    float p0 = scs[t][0], p1 = scs[t][1], p2 = scs[t][2], p3 = scs[t][3];
    float mx = fmaxf(fmaxf(p0, p1), fmaxf(p2, p3));
    float e0 = __expf(p0 - mx), e1 = __expf(p1 - mx), e2 = __expf(p2 - mx), e3 = __expf(p3 - mx);
    float inv = 1.0f / (e0 + e1 + e2 + e3);
    esm[t] = make_float4(e0 * inv, e1 * inv, e2 * inv, e3 * inv);
    int s = (t0b + t) & 4095;
    float g = 0.f;
#pragma unroll
    for (int tk = 0; tk < 7; tk++) {
      int ss = s + tk - 3;
      if (ss >= 0 && ss < SS)
        g += conv_w[tk] * pavg[bb * SS + ss] + conv_w[7 + tk] * pmax[bb * SS + ss];
    }
    gateb[t] = 1.0f / (1.0f + __expf(-g));
  }
  __syncthreads();

  // ---- windowed attention (swapped QK^T), wave w: window w>>1, col-half w&1 ----
  const int lane = t & 63, w = t >> 6;
  const int t0 = t0b + (w >> 1) * 16;         // window token base
  const int half = w & 1;
  const int qrow = lane & 15;
  const int grp8 = (lane >> 4) * 8;
  const int krow = (lane >> 4) * 4;

  const short* kqbase = &qkvb[(size_t)(t0 + qrow) * QKVS];
  f32x4 acc = (f32x4){0.f, 0.f, 0.f, 0.f};
#pragma unroll
  for (int k0 = 0; k0 < 512; k0 += 32) {
    bf16x8 kf = *(const bf16x8*)&kqbase[512 + k0 + grp8];
    bf16x8 qf = *(const bf16x8*)&kqbase[k0 + grp8];
    acc = __builtin_amdgcn_mfma_f32_16x16x32_bf16(kf, qf, acc, 0, 0, 0);
  }

  const float scale = 0.04419417382415922f;   // 1/sqrt(512)
  float s0 = acc[0] * scale, s1 = acc[1] * scale, s2 = acc[2] * scale, s3 = acc[3] * scale;
  float m = fmaxf(fmaxf(s0, s1), fmaxf(s2, s3));
  m = fmaxf(m, __shfl_xor(m, 16));
  m = fmaxf(m, __shfl_xor(m, 32));
  float e0 = __expf(s0 - m), e1 = __expf(s1 - m), e2 = __expf(s2 - m), e3 = __expf(s3 - m);
  float sum = e0 + e1 + e2 + e3;
  sum += __shfl_xor(sum, 16);
  sum += __shfl_xor(sum, 32);
  float inv = 1.0f / sum;
  s16x4 pa;
  pa[0] = f2bf(e0 * inv); pa[1] = f2bf(e1 * inv);
  pa[2] = f2bf(e2 * inv); pa[3] = f2bf(e3 * inv);

  // per-row (token) combine params for the 4 rows this lane writes
  float4 ee[4]; float ge[4];
#pragma unroll
  for (int jj = 0; jj < 4; jj++) {
    int rla = (w >> 1) * 16 + krow + jj;
    ee[jj] = esm[rla];
    ge[jj] = gateb[rla];
  }

  // ---- PV + combine epilogue ----
  const short* vbase = &qkvb[(size_t)t0 * QKVS + 1024];
  const float* kgr = &kgo[bb * 2048];
  const int colo = lane & 15;
#pragma unroll
  for (int ct = 0; ct < 16; ct++) {
    const int c0 = half * 256 + ct * 16 + colo;   // global col
    s16x4 bf;
#pragma unroll
    for (int u = 0; u < 4; u++)
      bf[u] = vbase[(size_t)(krow + u) * QKVS + c0 - colo + colo];  // V[k=krow+u][c0]
    f32x4 d = pv_mfma(pa, bf, (f32x4){0.f, 0.f, 0.f, 0.f});
    float k0v = kgr[c0], k1v = kgr[512 + c0], k2v = kgr[1024 + c0], k3v = kgr[1536 + c0];
    float bgov = bgo[c0];
#pragma unroll
    for (int jj = 0; jj < 4; jj++) {
      int row = t0 + krow + jj;
      float xg = ee[jj].x * k0v + ee[jj].y * k1v + ee[jj].z * k2v + ee[jj].w * k3v + bgov;
      float xv = bf2f(xb[(size_t)row * CC + c0]);
      y[(size_t)row * CC + c0] = f2bf((xv + d[jj] + xg) * ge[jj]);
    }
  }
}

// ---------------- fused kg+kgo: one block per (b,g) ----------------
__global__ __launch_bounds__(256) void kg_kgo_kernel(const float* __restrict__ x,
                                                     const float* __restrict__ Wg,
                                                     const float* __restrict__ bg,
                                                     const float* __restrict__ Wgo,
                                                     float* __restrict__ kg,
                                                     float* __restrict__ kgo)
{
  __shared__ float kr[128];
  const int bg_ = blockIdx.x;           // 0..31  (b = bg_>>2, g = bg_&3)
  const int b = bg_ >> 2, g = bg_ & 3;
  const int gidx[4] = {0, 1365, 2730, 4095};
  const int t = threadIdx.x;
  const float* xr = &x[((size_t)b * SS + gidx[g]) * CC];
  if (t < 128) {
    float s = bg[t];
    for (int c = 0; c < CC; c++) s += xr[c] * Wg[c * 128 + t];
    kr[t] = s;
    kg[bg_ * 128 + t] = s;
  }
  __syncthreads();
  for (int c = t; c < 512; c += 256) {
    float s = 0.f;
    for (int d = 0; d < 128; d++) s += kr[d] * Wgo[d * 512 + c];
    kgo[bg_ * 512 + c] = s;
  }
}

// ---------------- launcher ----------------
extern "C" void kernel_launch(void* const* d_in, const int* in_sizes, int n_in,
                              void* d_out, int out_size, void* d_ws, size_t ws_size,
                              hipStream_t stream)
{
  const float* x     = (const float*)d_in[0];
  const float* Wq    = (const float*)d_in[1];
  const float* bq    = (const float*)d_in[2];
  const float* Wk    = (const float*)d_in[3];
  const float* bk    = (const float*)d_in[4];
  const float* Wv    = (const float*)d_in[5];
  const float* bv    = (const float*)d_in[6];
  const float* Wo    = (const float*)d_in[7];
  const float* bo    = (const float*)d_in[8];
  const float* Wg    = (const float*)d_in[9];
  const float* bg    = (const float*)d_in[10];
  const float* Wgo   = (const float*)d_in[11];
  const float* bgo   = (const float*)d_in[12];
  const float* convw = (const float*)d_in[13];
  float* out = (float*)d_out;

  char* ws = (char*)d_ws;
  size_t off = 0;
  auto alloc = [&](size_t bytes) -> void* {
    void* p = ws + off;
    off += (bytes + 255) & ~(size_t)255;
    return p;
  };
  short* xb    = (short*)alloc((size_t)NTOK * CC * 2);           // 33.5 MB
  short* qkvb  = (short*)alloc((size_t)NTOK * QKVS * 2);         // 109 MB
  short* WtQKV = (short*)alloc((size_t)QKVS * 512 * 2);          // [q|k|v|WqWg] rows
  short* WtO   = (short*)alloc((size_t)512 * 512 * 2);
  short* WtG   = (short*)alloc((size_t)128 * 512 * 2);
  short* Wqb   = (short*)alloc((size_t)512 * 512 * 2);
  float* bqkv  = (float*)alloc(QKVS * 4);
  float* zb    = (float*)alloc(512 * 4);                         // FULL 512 zero bias
  float* kg    = (float*)alloc(8 * 4 * 128 * 4);
  float* kgo   = (float*)alloc(8 * 4 * 512 * 4);
  float* pavg  = (float*)alloc((size_t)NTOK * 4);
  float* pmax  = (float*)alloc((size_t)NTOK * 4);
  short* ybuf  = (short*)alloc((size_t)NTOK * CC * 2);           // 33.5 MB (final y)
  short* WtQG  = WtQKV + (size_t)1536 * 512;                     // tail rows of WtQKV

  prep_weights<<<3072, 256, 0, stream>>>(Wq, Wk, Wv, Wo, Wg, bq, bk, bv, bg,
                                         WtQKV, WtO, WtG, Wqb, bqkv, zb);
  cast_pool_kernel<<<NTOK / 4, 256, 0, stream>>>(x, xb, pavg, pmax);
  kg_kgo_kernel<<<32, 256, 0, stream>>>(x, Wg, bg, Wgo, kg, kgo);

  // WtQG[n][c] = (Wq@Wg)[c][n]:  nwg=4 (nx=4, one m-tile), no swizzle
  gemm_kernel<1, 0><<<4, 256, 0, stream>>>(WtG, Wqb, zb, WtQG, 512, 4);

  // qkv|qg = x @ [Wq|Wk|Wv|WqWg] + [bq|bk|bv|bqg]  (M=32768, N=1664), nwg=3328
  gemm_kernel<1, 1><<<13 * 256, 256, 0, stream>>>(xb, WtQKV, bqkv, qkvb, QKVS, 13);

  // fused window-attention + global-attn combine + gate -> y (bf16)
  winattn_combine_kernel<<<NTOK / 32, 256, 0, stream>>>(qkvb, xb, kg, kgo, bgo,
                                                        pavg, pmax, convw, ybuf);

  // out = y @ Wo + bo  (M=32768, N=512, fp32 out), nwg=1024
  gemm_kernel<0, 1><<<4 * 256, 256, 0, stream>>>(ybuf, WtO, bo, out, CC, 4);
}

// Round 8
// 217.078 us; speedup vs baseline: 1.2921x; 1.0975x over previous
//
#include <hip/hip_runtime.h>
#include <hip/hip_bf16.h>

#define BB 8
#define SS 4096
#define CC 512
#define NTOK (BB*SS)   // 32768
#define QKVS 1664      // q(512) | k(512) | v(512) | qg(128)

typedef __attribute__((ext_vector_type(8))) short bf16x8;
typedef __attribute__((ext_vector_type(4))) float f32x4;
typedef __attribute__((ext_vector_type(4))) short s16x4;

__device__ __forceinline__ float bf2f(short s) {
  return __uint_as_float(((unsigned)(unsigned short)s) << 16);
}
__device__ __forceinline__ short f2bf(float f) {
  __hip_bfloat16 h = __float2bfloat16(f);
  return *reinterpret_cast<short*>(&h);
}

__device__ __forceinline__ f32x4 pv_mfma(s16x4 a, s16x4 b, f32x4 c) {
#if __has_builtin(__builtin_amdgcn_mfma_f32_16x16x16bf16_1k)
  return __builtin_amdgcn_mfma_f32_16x16x16bf16_1k(a, b, c, 0, 0, 0);
#else
  f32x4 d;
  asm volatile("v_mfma_f32_16x16x16_bf16 %0, %1, %2, %3\n\ts_nop 7\n\ts_nop 7"
               : "=v"(d) : "v"(a), "v"(b), "v"(c));
  return d;
#endif
}

// async global -> LDS, 16B per lane; LDS dest is wave-uniform base + lane*16
__device__ __forceinline__ void gload_lds16(const short* g, short* l) {
  __builtin_amdgcn_global_load_lds(
      (const __attribute__((address_space(1))) unsigned int*)g,
      (__attribute__((address_space(3))) unsigned int*)l, 16, 0, 0);
}

// ---------------- prep: transpose+cast weights, bias concat, bqg, zero bias ----------------
__global__ __launch_bounds__(256) void prep_weights(
    const float* __restrict__ Wq, const float* __restrict__ Wk, const float* __restrict__ Wv,
    const float* __restrict__ Wo, const float* __restrict__ Wg,
    const float* __restrict__ bq, const float* __restrict__ bk, const float* __restrict__ bv,
    const float* __restrict__ bg,
    short* __restrict__ WtQKV, short* __restrict__ WtO, short* __restrict__ WtG,
    short* __restrict__ Wqb, float* __restrict__ bqkv, float* __restrict__ zb)
{
  int i = blockIdx.x * 256 + threadIdx.x;
  if (i < 1536 * 512) {                  // WtQKV[n][k] = W*(k, n%512)
    int n = i >> 9, k = i & 511;
    const float* W = (n < 512) ? Wq : (n < 1024) ? Wk : Wv;
    WtQKV[i] = f2bf(W[k * 512 + (n & 511)]);
  }
  if (i < 512 * 512) {                   // WtO[n][k] = Wo[k][n];  Wqb = bf16(Wq) row-major
    int n = i >> 9, k = i & 511;
    WtO[i] = f2bf(Wo[k * 512 + n]);
    Wqb[i] = f2bf(Wq[i]);
  }
  if (i < 128 * 512) {                   // WtG[n][k] = Wg[k][n]
    int n = i >> 9, k = i & 511;
    WtG[i] = f2bf(Wg[k * 128 + n]);
  }
  if (i < 1536) {
    bqkv[i] = (i < 512) ? bq[i] : (i < 1024) ? bk[i - 512] : bv[i - 1024];
  }
  if (i < 512) zb[i] = 0.f;              // zero bias — FULL 512 cols (fold GEMM N=512)
  if (i < 128) {                         // bqg[n] = bg[n] + sum_c bq[c]*Wg[c][n]
    float s = bg[i];
    for (int c = 0; c < 512; c++) s += bq[c] * Wg[c * 128 + i];
    bqkv[1536 + i] = s;
  }
}

// ---------------- fused: cast x fp32->bf16 + channel pool (avg,max) ----------------
__global__ __launch_bounds__(256) void cast_pool_kernel(const float* __restrict__ x,
                                                        short* __restrict__ xb,
                                                        float* __restrict__ pavg,
                                                        float* __restrict__ pmax)
{
  int tok = blockIdx.x * 4 + (threadIdx.x >> 6);
  int lane = threadIdx.x & 63;
  const float* xr = &x[(size_t)tok * CC];
  float4 a = *(const float4*)&xr[lane * 4];
  float4 b = *(const float4*)&xr[256 + lane * 4];
  s16x4 oa, ob;
  oa[0] = f2bf(a.x); oa[1] = f2bf(a.y); oa[2] = f2bf(a.z); oa[3] = f2bf(a.w);
  ob[0] = f2bf(b.x); ob[1] = f2bf(b.y); ob[2] = f2bf(b.z); ob[3] = f2bf(b.w);
  *(s16x4*)&xb[(size_t)tok * CC + lane * 4] = oa;
  *(s16x4*)&xb[(size_t)tok * CC + 256 + lane * 4] = ob;
  float s = (a.x + a.y) + (a.z + a.w) + (b.x + b.y) + (b.z + b.w);
  float m = fmaxf(fmaxf(fmaxf(a.x, a.y), fmaxf(a.z, a.w)),
                  fmaxf(fmaxf(b.x, b.y), fmaxf(b.z, b.w)));
#pragma unroll
  for (int off = 32; off; off >>= 1) {
    s += __shfl_down(s, off);
    m = fmaxf(m, __shfl_down(m, off));
  }
  if (lane == 0) { pavg[tok] = s * (1.0f / CC); pmax[tok] = m; }
}

// ---------------- bf16 MFMA GEMM, BK=64 single-buffer, XOR-swizzled LDS ----------------
template<int OUT_BF16, int SWZ>
__global__ __launch_bounds__(256, 3) void gemm_kernel(
    const short* __restrict__ A,
    const short* __restrict__ Wt,
    const float* __restrict__ bias,
    void* __restrict__ Cp, int ldc, int nx)
{
  __shared__ short As[128 * 64];
  __shared__ short Bs[128 * 64];
  int id = blockIdx.x;
  if (SWZ) {                              // T1: contiguous tile chunk per XCD (grid%8==0)
    const int cpx = gridDim.x >> 3;
    id = (id & 7) * cpx + (id >> 3);
  }
  const int n0 = (id % nx) * 128;
  const int m0 = (id / nx) * 128;
  const int t = threadIdx.x;
  const int lane = t & 63, w = t >> 6;
  const int wm = (w >> 1) * 64, wn = (w & 1) * 64;
  const int lr = lane & 15;
  const int g8b = (lane >> 4) * 16;       // byte offset of k-frag (8 bf16)
  const int xorb = (lr & 7) << 4;         // reader swizzle (row&7)<<4 bytes

  const int srow = w * 8 + (lane >> 3);
  const int scol = (((lane & 7) ^ (lane >> 3)) << 4) >> 1;    // elems
  const short* Ag = A + (size_t)(m0 + srow) * 512 + scol;
  const short* Bg = Wt + (size_t)(n0 + srow) * 512 + scol;
  short* Al = &As[(w * 8) * 64];
  short* Bl = &Bs[(w * 8) * 64];

  f32x4 acc[4][4];
#pragma unroll
  for (int i = 0; i < 4; i++)
#pragma unroll
    for (int j = 0; j < 4; j++) acc[i][j] = (f32x4){0.f, 0.f, 0.f, 0.f};

  for (int k0 = 0; k0 < 512; k0 += 64) {
#pragma unroll
    for (int s = 0; s < 4; s++) {
      gload_lds16(Ag + k0 + s * (32 * 512), Al + s * (32 * 64));
      gload_lds16(Bg + k0 + s * (32 * 512), Bl + s * (32 * 64));
    }
    __syncthreads();                     // implicit vmcnt(0) drain
#pragma unroll
    for (int kk = 0; kk < 2; kk++) {
      bf16x8 af[4], bfr[4];
      const int ko = ((kk * 64 + g8b) ^ xorb) >> 1;   // swizzled elem offset in row
#pragma unroll
      for (int mt = 0; mt < 4; mt++) af[mt]  = *(bf16x8*)&As[(wm + mt * 16 + lr) * 64 + ko];
#pragma unroll
      for (int nt = 0; nt < 4; nt++) bfr[nt] = *(bf16x8*)&Bs[(wn + nt * 16 + lr) * 64 + ko];
#pragma unroll
      for (int mt = 0; mt < 4; mt++)
#pragma unroll
        for (int nt = 0; nt < 4; nt++)
          acc[mt][nt] = __builtin_amdgcn_mfma_f32_16x16x32_bf16(af[mt], bfr[nt], acc[mt][nt], 0, 0, 0);
    }
    __syncthreads();
  }

  const int cr = (lane >> 4) * 4;
#pragma unroll
  for (int nt = 0; nt < 4; nt++) {
    int col = n0 + wn + nt * 16 + lr;
    float bv = bias[col];
#pragma unroll
    for (int mt = 0; mt < 4; mt++) {
      int row = m0 + wm + mt * 16 + cr;
#pragma unroll
      for (int j = 0; j < 4; j++) {
        float v = acc[mt][nt][j] + bv;
        if (OUT_BF16) ((short*)Cp)[(size_t)(row + j) * ldc + col] = f2bf(v);
        else          ((float*)Cp)[(size_t)(row + j) * ldc + col] = v;
      }
    }
  }
}

// ---------------- fused windowed attention + combine (v2: LDS transpose epilogue) ------
// Block = 4 waves, 2 windows (32 tokens). Phase 0: gattn softmax + conv gate -> LDS.
// QK^T swapped-MFMA per wave (2 acc chains); V prefetched to regs after QK loads (T14);
// PV -> xl in LDS [32][528] bf16; barrier; vectorized combine writes final y.
__global__ __launch_bounds__(256, 4) void winattn_combine_kernel(
    const short* __restrict__ qkvb, const short* __restrict__ xb,
    const float* __restrict__ kg, const float* __restrict__ kgo,
    const float* __restrict__ bgo, const float* __restrict__ pavg,
    const float* __restrict__ pmax, const float* __restrict__ conv_w,
    short* __restrict__ y)
{
  __shared__ short xls[32][528];              // row stride 1056 B (16B aligned)
  __shared__ float scs[32][4];
  __shared__ float4 esm[32];
  __shared__ float gateb[32];
  const int t = threadIdx.x;
  const int t0b = blockIdx.x * 32;            // block token base
  const int bb = t0b >> 12;                   // batch

  // ---- phase 0a: raw gattn scores (4 threads per token) ----
  if (t < 128) {
    const int tl = t >> 2, gi = t & 3;
    const short* qr = &qkvb[(size_t)(t0b + tl) * QKVS + 1536];
    const float* kr = &kg[bb * 512 + gi * 128];
    float s = 0.f;
    for (int d0 = 0; d0 < 128; d0 += 8) {
      bf16x8 qv = *(const bf16x8*)&qr[d0];
#pragma unroll
      for (int u = 0; u < 8; u++) s += bf2f(qv[u]) * kr[d0 + u];
    }
    scs[tl][gi] = s * 0.08838834764831845f;   // 1/sqrt(128)
  }
  __syncthreads();
  // ---- phase 0b: softmax + conv gate (1 thread per token) ----
  if (t < 32) {
    float p0 = scs[t][0], p1 = scs[t][1], p2 = scs[t][2], p3 = scs[t][3];
    float mx = fmaxf(fmaxf(p0, p1), fmaxf(p2, p3));
    float e0 = __expf(p0 - mx), e1 = __expf(p1 - mx), e2 = __expf(p2 - mx), e3 = __expf(p3 - mx);
    float inv = 1.0f / (e0 + e1 + e2 + e3);
    esm[t] = make_float4(e0 * inv, e1 * inv, e2 * inv, e3 * inv);
    int s = (t0b + t) & 4095;
    float g = 0.f;
#pragma unroll
    for (int tk = 0; tk < 7; tk++) {
      int ss = s + tk - 3;
      if (ss >= 0 && ss < SS)
        g += conv_w[tk] * pavg[bb * SS + ss] + conv_w[7 + tk] * pmax[bb * SS + ss];
    }
    gateb[t] = 1.0f / (1.0f + __expf(-g));
  }

  // ---- windowed attention (swapped QK^T), wave w: window w>>1, col-half w&1 ----
  const int lane = t & 63, w = t >> 6;
  const int t0 = t0b + (w >> 1) * 16;         // window token base
  const int half = w & 1;
  const int qrow = lane & 15;
  const int grp8 = (lane >> 4) * 8;
  const int krow = (lane >> 4) * 4;
  const int colo = lane & 15;

  const short* kqbase = &qkvb[(size_t)(t0 + qrow) * QKVS];
  f32x4 accA = (f32x4){0.f, 0.f, 0.f, 0.f};
  f32x4 accB = (f32x4){0.f, 0.f, 0.f, 0.f};
#pragma unroll
  for (int k0 = 0; k0 < 512; k0 += 64) {      // 2 independent chains
    bf16x8 kf0 = *(const bf16x8*)&kqbase[512 + k0 + grp8];
    bf16x8 qf0 = *(const bf16x8*)&kqbase[k0 + grp8];
    bf16x8 kf1 = *(const bf16x8*)&kqbase[512 + k0 + 32 + grp8];
    bf16x8 qf1 = *(const bf16x8*)&kqbase[k0 + 32 + grp8];
    accA = __builtin_amdgcn_mfma_f32_16x16x32_bf16(kf0, qf0, accA, 0, 0, 0);
    accB = __builtin_amdgcn_mfma_f32_16x16x32_bf16(kf1, qf1, accB, 0, 0, 0);
  }

  // ---- V prefetch (issued after QK loads; lands during softmax) ----
  const short* vbase = &qkvb[(size_t)t0 * QKVS + 1024];
  s16x4 vreg[16];
#pragma unroll
  for (int ct = 0; ct < 16; ct++) {
    const int c0 = half * 256 + ct * 16 + colo;
#pragma unroll
    for (int u = 0; u < 4; u++)
      vreg[ct][u] = vbase[(size_t)(krow + u) * QKVS + c0];
  }

  // ---- softmax over 16 keys ----
  const float scale = 0.04419417382415922f;   // 1/sqrt(512)
  float s0 = (accA[0] + accB[0]) * scale, s1 = (accA[1] + accB[1]) * scale;
  float s2 = (accA[2] + accB[2]) * scale, s3 = (accA[3] + accB[3]) * scale;
  float m = fmaxf(fmaxf(s0, s1), fmaxf(s2, s3));
  m = fmaxf(m, __shfl_xor(m, 16));
  m = fmaxf(m, __shfl_xor(m, 32));
  float e0 = __expf(s0 - m), e1 = __expf(s1 - m), e2 = __expf(s2 - m), e3 = __expf(s3 - m);
  float sum = e0 + e1 + e2 + e3;
  sum += __shfl_xor(sum, 16);
  sum += __shfl_xor(sum, 32);
  float inv = 1.0f / sum;
  s16x4 pa;
  pa[0] = f2bf(e0 * inv); pa[1] = f2bf(e1 * inv);
  pa[2] = f2bf(e2 * inv); pa[3] = f2bf(e3 * inv);

  // ---- PV -> LDS (xl transpose staging) ----
  const int rbase = (w >> 1) * 16 + krow;
#pragma unroll
  for (int ct = 0; ct < 16; ct++) {
    const int c0 = half * 256 + ct * 16 + colo;
    f32x4 d = pv_mfma(pa, vreg[ct], (f32x4){0.f, 0.f, 0.f, 0.f});
#pragma unroll
    for (int jj = 0; jj < 4; jj++)
      xls[rbase + jj][c0] = f2bf(d[jj]);
  }
  __syncthreads();

  // ---- vectorized combine: thread -> (row r=t>>3, cols (t&7)*8 + 64*it) ----
  const int r = t >> 3;
  const int rowg = t0b + r;
  const float4 e = esm[r];
  const float g = gateb[r];
  const float* kgr = &kgo[bb * 2048];
  const short* xrow = &xb[(size_t)rowg * CC];
  short* yrow = &y[(size_t)rowg * CC];
#pragma unroll
  for (int it = 0; it < 8; it++) {
    const int c = (t & 7) * 8 + it * 64;
    bf16x8 xv  = *(const bf16x8*)&xrow[c];
    bf16x8 xlv = *(const bf16x8*)&xls[r][c];
    float4 k0a = *(const float4*)&kgr[c],        k0b = *(const float4*)&kgr[c + 4];
    float4 k1a = *(const float4*)&kgr[512 + c],  k1b = *(const float4*)&kgr[512 + c + 4];
    float4 k2a = *(const float4*)&kgr[1024 + c], k2b = *(const float4*)&kgr[1024 + c + 4];
    float4 k3a = *(const float4*)&kgr[1536 + c], k3b = *(const float4*)&kgr[1536 + c + 4];
    float4 ba  = *(const float4*)&bgo[c],        bbv = *(const float4*)&bgo[c + 4];
    float xg[8];
    xg[0] = e.x * k0a.x + e.y * k1a.x + e.z * k2a.x + e.w * k3a.x + ba.x;
    xg[1] = e.x * k0a.y + e.y * k1a.y + e.z * k2a.y + e.w * k3a.y + ba.y;
    xg[2] = e.x * k0a.z + e.y * k1a.z + e.z * k2a.z + e.w * k3a.z + ba.z;
    xg[3] = e.x * k0a.w + e.y * k1a.w + e.z * k2a.w + e.w * k3a.w + ba.w;
    xg[4] = e.x * k0b.x + e.y * k1b.x + e.z * k2b.x + e.w * k3b.x + bbv.x;
    xg[5] = e.x * k0b.y + e.y * k1b.y + e.z * k2b.y + e.w * k3b.y + bbv.y;
    xg[6] = e.x * k0b.z + e.y * k1b.z + e.z * k2b.z + e.w * k3b.z + bbv.z;
    xg[7] = e.x * k0b.w + e.y * k1b.w + e.z * k2b.w + e.w * k3b.w + bbv.w;
    bf16x8 ov;
#pragma unroll
    for (int u = 0; u < 8; u++)
      ov[u] = f2bf((bf2f(xv[u]) + bf2f(xlv[u]) + xg[u]) * g);
    *(bf16x8*)&yrow[c] = ov;
  }
}

// ---------------- fused kg+kgo: one block per (b,g) ----------------
__global__ __launch_bounds__(256) void kg_kgo_kernel(const float* __restrict__ x,
                                                     const float* __restrict__ Wg,
                                                     const float* __restrict__ bg,
                                                     const float* __restrict__ Wgo,
                                                     float* __restrict__ kg,
                                                     float* __restrict__ kgo)
{
  __shared__ float kr[128];
  const int bg_ = blockIdx.x;           // 0..31  (b = bg_>>2, g = bg_&3)
  const int b = bg_ >> 2, g = bg_ & 3;
  const int gidx[4] = {0, 1365, 2730, 4095};
  const int t = threadIdx.x;
  const float* xr = &x[((size_t)b * SS + gidx[g]) * CC];
  if (t < 128) {
    float s = bg[t];
    for (int c = 0; c < CC; c++) s += xr[c] * Wg[c * 128 + t];
    kr[t] = s;
    kg[bg_ * 128 + t] = s;
  }
  __syncthreads();
  for (int c = t; c < 512; c += 256) {
    float s = 0.f;
    for (int d = 0; d < 128; d++) s += kr[d] * Wgo[d * 512 + c];
    kgo[bg_ * 512 + c] = s;
  }
}

// ---------------- launcher ----------------
extern "C" void kernel_launch(void* const* d_in, const int* in_sizes, int n_in,
                              void* d_out, int out_size, void* d_ws, size_t ws_size,
                              hipStream_t stream)
{
  const float* x     = (const float*)d_in[0];
  const float* Wq    = (const float*)d_in[1];
  const float* bq    = (const float*)d_in[2];
  const float* Wk    = (const float*)d_in[3];
  const float* bk    = (const float*)d_in[4];
  const float* Wv    = (const float*)d_in[5];
  const float* bv    = (const float*)d_in[6];
  const float* Wo    = (const float*)d_in[7];
  const float* bo    = (const float*)d_in[8];
  const float* Wg    = (const float*)d_in[9];
  const float* bg    = (const float*)d_in[10];
  const float* Wgo   = (const float*)d_in[11];
  const float* bgo   = (const float*)d_in[12];
  const float* convw = (const float*)d_in[13];
  float* out = (float*)d_out;

  char* ws = (char*)d_ws;
  size_t off = 0;
  auto alloc = [&](size_t bytes) -> void* {
    void* p = ws + off;
    off += (bytes + 255) & ~(size_t)255;
    return p;
  };
  short* xb    = (short*)alloc((size_t)NTOK * CC * 2);           // 33.5 MB
  short* qkvb  = (short*)alloc((size_t)NTOK * QKVS * 2);         // 109 MB
  short* WtQKV = (short*)alloc((size_t)QKVS * 512 * 2);          // [q|k|v|WqWg] rows
  short* WtO   = (short*)alloc((size_t)512 * 512 * 2);
  short* WtG   = (short*)alloc((size_t)128 * 512 * 2);
  short* Wqb   = (short*)alloc((size_t)512 * 512 * 2);
  float* bqkv  = (float*)alloc(QKVS * 4);
  float* zb    = (float*)alloc(512 * 4);                         // FULL 512 zero bias
  float* kg    = (float*)alloc(8 * 4 * 128 * 4);
  float* kgo   = (float*)alloc(8 * 4 * 512 * 4);
  float* pavg  = (float*)alloc((size_t)NTOK * 4);
  float* pmax  = (float*)alloc((size_t)NTOK * 4);
  short* ybuf  = (short*)alloc((size_t)NTOK * CC * 2);           // 33.5 MB (final y)
  short* WtQG  = WtQKV + (size_t)1536 * 512;                     // tail rows of WtQKV

  prep_weights<<<3072, 256, 0, stream>>>(Wq, Wk, Wv, Wo, Wg, bq, bk, bv, bg,
                                         WtQKV, WtO, WtG, Wqb, bqkv, zb);
  cast_pool_kernel<<<NTOK / 4, 256, 0, stream>>>(x, xb, pavg, pmax);
  kg_kgo_kernel<<<32, 256, 0, stream>>>(x, Wg, bg, Wgo, kg, kgo);

  // WtQG[n][c] = (Wq@Wg)[c][n]:  nwg=4 (nx=4, one m-tile), no swizzle
  gemm_kernel<1, 0><<<4, 256, 0, stream>>>(WtG, Wqb, zb, WtQG, 512, 4);

  // qkv|qg = x @ [Wq|Wk|Wv|WqWg] + [bq|bk|bv|bqg]  (M=32768, N=1664), nwg=3328
  gemm_kernel<1, 1><<<13 * 256, 256, 0, stream>>>(xb, WtQKV, bqkv, qkvb, QKVS, 13);

  // fused window-attention + global-attn combine + gate -> y (bf16)
  winattn_combine_kernel<<<NTOK / 32, 256, 0, stream>>>(qkvb, xb, kg, kgo, bgo,
                                                        pavg, pmax, convw, ybuf);

  // out = y @ Wo + bo  (M=32768, N=512, fp32 out), nwg=1024
  gemm_kernel<0, 1><<<4 * 256, 256, 0, stream>>>(ybuf, WtO, bo, out, CC, 4);
}

// Round 9
// 213.167 us; speedup vs baseline: 1.3158x; 1.0183x over previous
//
#include <hip/hip_runtime.h>
#include <hip/hip_bf16.h>

#define BB 8
#define SS 4096
#define CC 512
#define NTOK (BB*SS)   // 32768
#define QKVS 1664      // q(512) | k(512) | v(512) | qg(128)

typedef __attribute__((ext_vector_type(8))) short bf16x8;
typedef __attribute__((ext_vector_type(4))) float f32x4;
typedef __attribute__((ext_vector_type(4))) short s16x4;

__device__ __forceinline__ float bf2f(short s) {
  return __uint_as_float(((unsigned)(unsigned short)s) << 16);
}
__device__ __forceinline__ short f2bf(float f) {
  __hip_bfloat16 h = __float2bfloat16(f);
  return *reinterpret_cast<short*>(&h);
}

__device__ __forceinline__ f32x4 pv_mfma(s16x4 a, s16x4 b, f32x4 c) {
#if __has_builtin(__builtin_amdgcn_mfma_f32_16x16x16bf16_1k)
  return __builtin_amdgcn_mfma_f32_16x16x16bf16_1k(a, b, c, 0, 0, 0);
#else
  f32x4 d;
  asm volatile("v_mfma_f32_16x16x16_bf16 %0, %1, %2, %3\n\ts_nop 7\n\ts_nop 7"
               : "=v"(d) : "v"(a), "v"(b), "v"(c));
  return d;
#endif
}

// async global -> LDS, 16B per lane; LDS dest is wave-uniform base + lane*16
__device__ __forceinline__ void gload_lds16(const short* g, short* l) {
  __builtin_amdgcn_global_load_lds(
      (const __attribute__((address_space(1))) unsigned int*)g,
      (__attribute__((address_space(3))) unsigned int*)l, 16, 0, 0);
}

// ---------------- prep: transpose+cast weights, bias concat, bqg, zero bias ----------------
__global__ __launch_bounds__(256) void prep_weights(
    const float* __restrict__ Wq, const float* __restrict__ Wk, const float* __restrict__ Wv,
    const float* __restrict__ Wo, const float* __restrict__ Wg,
    const float* __restrict__ bq, const float* __restrict__ bk, const float* __restrict__ bv,
    const float* __restrict__ bg,
    short* __restrict__ WtQKV, short* __restrict__ WtO, short* __restrict__ WtG,
    short* __restrict__ Wqb, float* __restrict__ bqkv, float* __restrict__ zb)
{
  int i = blockIdx.x * 256 + threadIdx.x;
  if (i < 1536 * 512) {                  // WtQKV[n][k] = W*(k, n%512)
    int n = i >> 9, k = i & 511;
    const float* W = (n < 512) ? Wq : (n < 1024) ? Wk : Wv;
    WtQKV[i] = f2bf(W[k * 512 + (n & 511)]);
  }
  if (i < 512 * 512) {                   // WtO[n][k] = Wo[k][n];  Wqb = bf16(Wq) row-major
    int n = i >> 9, k = i & 511;
    WtO[i] = f2bf(Wo[k * 512 + n]);
    Wqb[i] = f2bf(Wq[i]);
  }
  if (i < 128 * 512) {                   // WtG[n][k] = Wg[k][n]
    int n = i >> 9, k = i & 511;
    WtG[i] = f2bf(Wg[k * 128 + n]);
  }
  if (i < 1536) {
    bqkv[i] = (i < 512) ? bq[i] : (i < 1024) ? bk[i - 512] : bv[i - 1024];
  }
  if (i < 512) zb[i] = 0.f;              // zero bias — FULL 512 cols (fold GEMM N=512)
  if (i < 128) {                         // bqg[n] = bg[n] + sum_c bq[c]*Wg[c][n]
    float s = bg[i];
    for (int c = 0; c < 512; c++) s += bq[c] * Wg[c * 128 + i];
    bqkv[1536 + i] = s;
  }
}

// ---------------- fused: cast x fp32->bf16 + channel pool (avg,max) ----------------
__global__ __launch_bounds__(256) void cast_pool_kernel(const float* __restrict__ x,
                                                        short* __restrict__ xb,
                                                        float* __restrict__ pavg,
                                                        float* __restrict__ pmax)
{
  int tok = blockIdx.x * 4 + (threadIdx.x >> 6);
  int lane = threadIdx.x & 63;
  const float* xr = &x[(size_t)tok * CC];
  float4 a = *(const float4*)&xr[lane * 4];
  float4 b = *(const float4*)&xr[256 + lane * 4];
  s16x4 oa, ob;
  oa[0] = f2bf(a.x); oa[1] = f2bf(a.y); oa[2] = f2bf(a.z); oa[3] = f2bf(a.w);
  ob[0] = f2bf(b.x); ob[1] = f2bf(b.y); ob[2] = f2bf(b.z); ob[3] = f2bf(b.w);
  *(s16x4*)&xb[(size_t)tok * CC + lane * 4] = oa;
  *(s16x4*)&xb[(size_t)tok * CC + 256 + lane * 4] = ob;
  float s = (a.x + a.y) + (a.z + a.w) + (b.x + b.y) + (b.z + b.w);
  float m = fmaxf(fmaxf(fmaxf(a.x, a.y), fmaxf(a.z, a.w)),
                  fmaxf(fmaxf(b.x, b.y), fmaxf(b.z, b.w)));
#pragma unroll
  for (int off = 32; off; off >>= 1) {
    s += __shfl_down(s, off);
    m = fmaxf(m, __shfl_down(m, off));
  }
  if (lane == 0) { pavg[tok] = s * (1.0f / CC); pmax[tok] = m; }
}

// ---------------- bf16 MFMA GEMM, BK=64, 2-phase dbuf, ONE barrier per K-tile ----------
// C[M,N] = A[M,512] @ Wt[N,512]^T + bias. tile 128x128, 4 waves (2x2), wave 64x64.
// Separate named LDS buffers (As0/As1) so the compiler can prove the in-flight
// global_load_lds (next tile) doesn't alias the ds_read (current tile).
// XOR-swizzle both sides (rule 21): stage source chunk ^= row&7; reader ^= (row&7)<<4 B.
template<int OUT_BF16, int SWZ>
__global__ __launch_bounds__(256, 2) void gemm_kernel(
    const short* __restrict__ A,
    const short* __restrict__ Wt,
    const float* __restrict__ bias,
    void* __restrict__ Cp, int ldc, int nx)
{
  __shared__ short As0[128 * 64], As1[128 * 64];
  __shared__ short Bs0[128 * 64], Bs1[128 * 64];
  int id = blockIdx.x;
  if (SWZ) {                              // T1: contiguous tile chunk per XCD (grid%8==0)
    const int cpx = gridDim.x >> 3;
    id = (id & 7) * cpx + (id >> 3);
  }
  const int n0 = (id % nx) * 128;
  const int m0 = (id / nx) * 128;
  const int t = threadIdx.x;
  const int lane = t & 63, w = t >> 6;
  const int wm = (w >> 1) * 64, wn = (w & 1) * 64;
  const int lr = lane & 15;
  const int g8b = (lane >> 4) * 16;       // byte offset of k-frag (8 bf16)
  const int xorb = (lr & 7) << 4;         // reader swizzle (row&7)<<4 bytes

  // staging: per sub-stage s, wave w covers rows s*32 + w*8 + (lane>>3), 16B per lane;
  // source chunk pre-XORed with row&7 (== lane>>3) so linear LDS holds swizzled data.
  const int srow = w * 8 + (lane >> 3);
  const int scol = (((lane & 7) ^ (lane >> 3)) << 4) >> 1;    // elems
  const short* Ag = A + (size_t)(m0 + srow) * 512 + scol;
  const short* Bg = Wt + (size_t)(n0 + srow) * 512 + scol;
  const int sloff = (w * 8) * 64;         // wave-uniform LDS row offset

  f32x4 acc[4][4];
#pragma unroll
  for (int i = 0; i < 4; i++)
#pragma unroll
    for (int j = 0; j < 4; j++) acc[i][j] = (f32x4){0.f, 0.f, 0.f, 0.f};

#define STAGE(AL, BL, KOFF)                                          \
  do {                                                               \
    _Pragma("unroll")                                                \
    for (int s_ = 0; s_ < 4; s_++) {                                 \
      gload_lds16(Ag + (KOFF) + s_ * (32 * 512), &AL[sloff + s_ * (32 * 64)]); \
      gload_lds16(Bg + (KOFF) + s_ * (32 * 512), &BL[sloff + s_ * (32 * 64)]); \
    }                                                                \
  } while (0)

#define COMPUTE(AL, BL)                                                           \
  do {                                                                            \
    _Pragma("unroll")                                                             \
    for (int kk = 0; kk < 2; kk++) {                                              \
      bf16x8 af[4], bfr[4];                                                       \
      const int ko = ((kk * 64 + g8b) ^ xorb) >> 1;                               \
      _Pragma("unroll")                                                           \
      for (int mt = 0; mt < 4; mt++) af[mt]  = *(bf16x8*)&AL[(wm + mt * 16 + lr) * 64 + ko]; \
      _Pragma("unroll")                                                           \
      for (int nt = 0; nt < 4; nt++) bfr[nt] = *(bf16x8*)&BL[(wn + nt * 16 + lr) * 64 + ko]; \
      _Pragma("unroll")                                                           \
      for (int mt = 0; mt < 4; mt++)                                              \
        _Pragma("unroll")                                                         \
        for (int nt = 0; nt < 4; nt++)                                            \
          acc[mt][nt] = __builtin_amdgcn_mfma_f32_16x16x32_bf16(af[mt], bfr[nt], acc[mt][nt], 0, 0, 0); \
    }                                                                             \
  } while (0)

  STAGE(As0, Bs0, 0);
  __syncthreads();                        // prologue drain
#pragma unroll
  for (int tt = 0; tt < 3; tt++) {
    STAGE(As1, Bs1, tt * 128 + 64);       // prefetch overlaps compute below
    COMPUTE(As0, Bs0);
    __syncthreads();                      // drains prefetch; all done reading As0
    STAGE(As0, Bs0, tt * 128 + 128);
    COMPUTE(As1, Bs1);
    __syncthreads();
  }
  STAGE(As1, Bs1, 448);
  COMPUTE(As0, Bs0);                      // k=384
  __syncthreads();
  COMPUTE(As1, Bs1);                      // k=448
#undef STAGE
#undef COMPUTE

  // epilogue: D mapping col=lane&15, row=(lane>>4)*4+j
  const int cr = (lane >> 4) * 4;
#pragma unroll
  for (int nt = 0; nt < 4; nt++) {
    int col = n0 + wn + nt * 16 + lr;
    float bv = bias[col];
#pragma unroll
    for (int mt = 0; mt < 4; mt++) {
      int row = m0 + wm + mt * 16 + cr;
#pragma unroll
      for (int j = 0; j < 4; j++) {
        float v = acc[mt][nt][j] + bv;
        if (OUT_BF16) ((short*)Cp)[(size_t)(row + j) * ldc + col] = f2bf(v);
        else          ((float*)Cp)[(size_t)(row + j) * ldc + col] = v;
      }
    }
  }
}

// ---------------- fused windowed attention + combine (v3: V via swizzled gload_lds) ----
// Block = 4 waves, 2 windows (32 tokens). V staged to LDS first (vectorized, swizzled
// source; latency hides under phase0 + QK^T). PV reads V from LDS (2-way conflict) and
// overwrites each consumed V subtile with xl in place. Combine reads xl swizzled.
__global__ __launch_bounds__(256, 4) void winattn_combine_kernel(
    const short* __restrict__ qkvb, const short* __restrict__ xb,
    const float* __restrict__ kg, const float* __restrict__ kgo,
    const float* __restrict__ bgo, const float* __restrict__ pavg,
    const float* __restrict__ pmax, const float* __restrict__ conv_w,
    short* __restrict__ y)
{
  __shared__ short vs[2][16][512];            // V then xl, row-linear, data swizzled
  __shared__ float scs[32][4];
  __shared__ float4 esm[32];
  __shared__ float gateb[32];
  const int t = threadIdx.x;
  const int lane = t & 63, w = t >> 6;
  const int t0b = blockIdx.x * 32;            // block token base
  const int bb = t0b >> 12;                   // batch
  const int win = w >> 1, half = w & 1;
  const int t0 = t0b + win * 16;              // window token base

  // ---- V stage: wave covers rows half*8..+7 of its window; chunk l -> l^(r&7) ----
  {
    const int rb = half * 8;
#pragma unroll
    for (int i = 0; i < 8; i++) {
      const int r = rb + i;
      const short* vrow = &qkvb[(size_t)(t0 + r) * QKVS + 1024];
      gload_lds16(vrow + ((lane ^ (r & 7)) << 3), &vs[win][r][0]);
    }
  }

  // ---- phase 0a: raw gattn scores (4 threads per token) ----
  if (t < 128) {
    const int tl = t >> 2, gi = t & 3;
    const short* qr = &qkvb[(size_t)(t0b + tl) * QKVS + 1536];
    const float* kr = &kg[bb * 512 + gi * 128];
    float s = 0.f;
    for (int d0 = 0; d0 < 128; d0 += 8) {
      bf16x8 qv = *(const bf16x8*)&qr[d0];
#pragma unroll
      for (int u = 0; u < 8; u++) s += bf2f(qv[u]) * kr[d0 + u];
    }
    scs[tl][gi] = s * 0.08838834764831845f;   // 1/sqrt(128)
  }
  __syncthreads();                            // scs ready; also drains V gload_lds
  // ---- phase 0b: softmax + conv gate (1 thread per token) ----
  if (t < 32) {
    float p0 = scs[t][0], p1 = scs[t][1], p2 = scs[t][2], p3 = scs[t][3];
    float mx = fmaxf(fmaxf(p0, p1), fmaxf(p2, p3));
    float e0 = __expf(p0 - mx), e1 = __expf(p1 - mx), e2 = __expf(p2 - mx), e3 = __expf(p3 - mx);
    float inv = 1.0f / (e0 + e1 + e2 + e3);
    esm[t] = make_float4(e0 * inv, e1 * inv, e2 * inv, e3 * inv);
    int s = (t0b + t) & 4095;
    float g = 0.f;
#pragma unroll
    for (int tk = 0; tk < 7; tk++) {
      int ss = s + tk - 3;
      if (ss >= 0 && ss < SS)
        g += conv_w[tk] * pavg[bb * SS + ss] + conv_w[7 + tk] * pmax[bb * SS + ss];
    }
    gateb[t] = 1.0f / (1.0f + __expf(-g));
  }

  // ---- QK^T (swapped, 2 acc chains) ----
  const int qrow = lane & 15;
  const int grp8 = (lane >> 4) * 8;
  const int krow = (lane >> 4) * 4;
  const int colo = lane & 15;

  const short* kqbase = &qkvb[(size_t)(t0 + qrow) * QKVS];
  f32x4 accA = (f32x4){0.f, 0.f, 0.f, 0.f};
  f32x4 accB = (f32x4){0.f, 0.f, 0.f, 0.f};
#pragma unroll
  for (int k0 = 0; k0 < 512; k0 += 64) {
    bf16x8 kf0 = *(const bf16x8*)&kqbase[512 + k0 + grp8];
    bf16x8 qf0 = *(const bf16x8*)&kqbase[k0 + grp8];
    bf16x8 kf1 = *(const bf16x8*)&kqbase[512 + k0 + 32 + grp8];
    bf16x8 qf1 = *(const bf16x8*)&kqbase[k0 + 32 + grp8];
    accA = __builtin_amdgcn_mfma_f32_16x16x32_bf16(kf0, qf0, accA, 0, 0, 0);
    accB = __builtin_amdgcn_mfma_f32_16x16x32_bf16(kf1, qf1, accB, 0, 0, 0);
  }

  // ---- softmax over 16 keys ----
  const float scale = 0.04419417382415922f;   // 1/sqrt(512)
  float s0 = (accA[0] + accB[0]) * scale, s1 = (accA[1] + accB[1]) * scale;
  float s2 = (accA[2] + accB[2]) * scale, s3 = (accA[3] + accB[3]) * scale;
  float m = fmaxf(fmaxf(s0, s1), fmaxf(s2, s3));
  m = fmaxf(m, __shfl_xor(m, 16));
  m = fmaxf(m, __shfl_xor(m, 32));
  float e0 = __expf(s0 - m), e1 = __expf(s1 - m), e2 = __expf(s2 - m), e3 = __expf(s3 - m);
  float sum = e0 + e1 + e2 + e3;
  sum += __shfl_xor(sum, 16);
  sum += __shfl_xor(sum, 32);
  float inv = 1.0f / sum;
  s16x4 pa;
  pa[0] = f2bf(e0 * inv); pa[1] = f2bf(e1 * inv);
  pa[2] = f2bf(e2 * inv); pa[3] = f2bf(e3 * inv);

  // ---- PV: read V from LDS (swizzled), mfma, overwrite consumed subtile with xl ----
#pragma unroll
  for (int ct = 0; ct < 16; ct++) {
    const int cb = (half * 256 + ct * 16 + colo) * 2;   // byte offset in row
    s16x4 bf;
#pragma unroll
    for (int u = 0; u < 4; u++) {
      const int r = krow + u;
      bf[u] = vs[win][r][(cb ^ ((r & 7) << 4)) >> 1];
    }
    f32x4 d = pv_mfma(pa, bf, (f32x4){0.f, 0.f, 0.f, 0.f});
#pragma unroll
    for (int jj = 0; jj < 4; jj++) {
      const int r = krow + jj;                          // D row = q index
      vs[win][r][(cb ^ ((r & 7) << 4)) >> 1] = f2bf(d[jj]);
    }
  }
  __syncthreads();

  // ---- vectorized combine: thread -> (row r=t>>3, cols (t&7)*8 + 64*it) ----
  const int r = t >> 3;
  const int rowg = t0b + r;
  const int winr = r >> 4, rr = r & 15;
  const float4 e = esm[r];
  const float g = gateb[r];
  const float* kgr = &kgo[bb * 2048];
  const short* xrow = &xb[(size_t)rowg * CC];
  const short* xlrow = &vs[winr][rr][0];
  short* yrow = &y[(size_t)rowg * CC];
#pragma unroll
  for (int it = 0; it < 8; it++) {
    const int c = (t & 7) * 8 + it * 64;
    bf16x8 xv  = *(const bf16x8*)&xrow[c];
    bf16x8 xlv = *(const bf16x8*)&xlrow[((c * 2) ^ ((rr & 7) << 4)) >> 1];
    float4 k0a = *(const float4*)&kgr[c],        k0b = *(const float4*)&kgr[c + 4];
    float4 k1a = *(const float4*)&kgr[512 + c],  k1b = *(const float4*)&kgr[512 + c + 4];
    float4 k2a = *(const float4*)&kgr[1024 + c], k2b = *(const float4*)&kgr[1024 + c + 4];
    float4 k3a = *(const float4*)&kgr[1536 + c], k3b = *(const float4*)&kgr[1536 + c + 4];
    float4 ba  = *(const float4*)&bgo[c],        bbv = *(const float4*)&bgo[c + 4];
    float xg[8];
    xg[0] = e.x * k0a.x + e.y * k1a.x + e.z * k2a.x + e.w * k3a.x + ba.x;
    xg[1] = e.x * k0a.y + e.y * k1a.y + e.z * k2a.y + e.w * k3a.y + ba.y;
    xg[2] = e.x * k0a.z + e.y * k1a.z + e.z * k2a.z + e.w * k3a.z + ba.z;
    xg[3] = e.x * k0a.w + e.y * k1a.w + e.z * k2a.w + e.w * k3a.w + ba.w;
    xg[4] = e.x * k0b.x + e.y * k1b.x + e.z * k2b.x + e.w * k3b.x + bbv.x;
    xg[5] = e.x * k0b.y + e.y * k1b.y + e.z * k2b.y + e.w * k3b.y + bbv.y;
    xg[6] = e.x * k0b.z + e.y * k1b.z + e.z * k2b.z + e.w * k3b.z + bbv.z;
    xg[7] = e.x * k0b.w + e.y * k1b.w + e.z * k2b.w + e.w * k3b.w + bbv.w;
    bf16x8 ov;
#pragma unroll
    for (int u = 0; u < 8; u++)
      ov[u] = f2bf((bf2f(xv[u]) + bf2f(xlv[u]) + xg[u]) * g);
    *(bf16x8*)&yrow[c] = ov;
  }
}

// ---------------- fused kg+kgo: one block per (b,g) ----------------
__global__ __launch_bounds__(256) void kg_kgo_kernel(const float* __restrict__ x,
                                                     const float* __restrict__ Wg,
                                                     const float* __restrict__ bg,
                                                     const float* __restrict__ Wgo,
                                                     float* __restrict__ kg,
                                                     float* __restrict__ kgo)
{
  __shared__ float kr[128];
  const int bg_ = blockIdx.x;           // 0..31  (b = bg_>>2, g = bg_&3)
  const int b = bg_ >> 2, g = bg_ & 3;
  const int gidx[4] = {0, 1365, 2730, 4095};
  const int t = threadIdx.x;
  const float* xr = &x[((size_t)b * SS + gidx[g]) * CC];
  if (t < 128) {
    float s = bg[t];
    for (int c = 0; c < CC; c++) s += xr[c] * Wg[c * 128 + t];
    kr[t] = s;
    kg[bg_ * 128 + t] = s;
  }
  __syncthreads();
  for (int c = t; c < 512; c += 256) {
    float s = 0.f;
    for (int d = 0; d < 128; d++) s += kr[d] * Wgo[d * 512 + c];
    kgo[bg_ * 512 + c] = s;
  }
}

// ---------------- launcher ----------------
extern "C" void kernel_launch(void* const* d_in, const int* in_sizes, int n_in,
                              void* d_out, int out_size, void* d_ws, size_t ws_size,
                              hipStream_t stream)
{
  const float* x     = (const float*)d_in[0];
  const float* Wq    = (const float*)d_in[1];
  const float* bq    = (const float*)d_in[2];
  const float* Wk    = (const float*)d_in[3];
  const float* bk    = (const float*)d_in[4];
  const float* Wv    = (const float*)d_in[5];
  const float* bv    = (const float*)d_in[6];
  const float* Wo    = (const float*)d_in[7];
  const float* bo    = (const float*)d_in[8];
  const float* Wg    = (const float*)d_in[9];
  const float* bg    = (const float*)d_in[10];
  const float* Wgo   = (const float*)d_in[11];
  const float* bgo   = (const float*)d_in[12];
  const float* convw = (const float*)d_in[13];
  float* out = (float*)d_out;

  char* ws = (char*)d_ws;
  size_t off = 0;
  auto alloc = [&](size_t bytes) -> void* {
    void* p = ws + off;
    off += (bytes + 255) & ~(size_t)255;
    return p;
  };
  short* xb    = (short*)alloc((size_t)NTOK * CC * 2);           // 33.5 MB
  short* qkvb  = (short*)alloc((size_t)NTOK * QKVS * 2);         // 109 MB
  short* WtQKV = (short*)alloc((size_t)QKVS * 512 * 2);          // [q|k|v|WqWg] rows
  short* WtO   = (short*)alloc((size_t)512 * 512 * 2);
  short* WtG   = (short*)alloc((size_t)128 * 512 * 2);
  short* Wqb   = (short*)alloc((size_t)512 * 512 * 2);
  float* bqkv  = (float*)alloc(QKVS * 4);
  float* zb    = (float*)alloc(512 * 4);                         // FULL 512 zero bias
  float* kg    = (float*)alloc(8 * 4 * 128 * 4);
  float* kgo   = (float*)alloc(8 * 4 * 512 * 4);
  float* pavg  = (float*)alloc((size_t)NTOK * 4);
  float* pmax  = (float*)alloc((size_t)NTOK * 4);
  short* ybuf  = (short*)alloc((size_t)NTOK * CC * 2);           // 33.5 MB (final y)
  short* WtQG  = WtQKV + (size_t)1536 * 512;                     // tail rows of WtQKV

  prep_weights<<<3072, 256, 0, stream>>>(Wq, Wk, Wv, Wo, Wg, bq, bk, bv, bg,
                                         WtQKV, WtO, WtG, Wqb, bqkv, zb);
  cast_pool_kernel<<<NTOK / 4, 256, 0, stream>>>(x, xb, pavg, pmax);
  kg_kgo_kernel<<<32, 256, 0, stream>>>(x, Wg, bg, Wgo, kg, kgo);

  // WtQG[n][c] = (Wq@Wg)[c][n]:  nwg=4 (nx=4, one m-tile), no swizzle
  gemm_kernel<1, 0><<<4, 256, 0, stream>>>(WtG, Wqb, zb, WtQG, 512, 4);

  // qkv|qg = x @ [Wq|Wk|Wv|WqWg] + [bq|bk|bv|bqg]  (M=32768, N=1664), nwg=3328
  gemm_kernel<1, 1><<<13 * 256, 256, 0, stream>>>(xb, WtQKV, bqkv, qkvb, QKVS, 13);

  // fused window-attention + global-attn combine + gate -> y (bf16)
  winattn_combine_kernel<<<NTOK / 32, 256, 0, stream>>>(qkvb, xb, kg, kgo, bgo,
                                                        pavg, pmax, convw, ybuf);

  // out = y @ Wo + bo  (M=32768, N=512, fp32 out), nwg=1024
  gemm_kernel<0, 1><<<4 * 256, 256, 0, stream>>>(ybuf, WtO, bo, out, CC, 4);
}